// Round 2
// baseline (268.155 us; speedup 1.0000x reference)
//
#include <hip/hip_runtime.h>
#include <hip/hip_bf16.h>
#include <math.h>

typedef __bf16 bf16_t;
typedef __bf16 bf16x4_t __attribute__((ext_vector_type(4)));
typedef __bf16 bf16x8_t __attribute__((ext_vector_type(8)));
typedef float  f32x4_t  __attribute__((ext_vector_type(4)));

#define SEQ 2048
#define DM  1024
#define NH  16
#define DK  64
// log2(10000)/32
#define ROPE_C 0.4152410118609203f
// log2(e)/sqrt(dk)
#define EXP_C (1.4426950408889634f / 8.0f)

// async global->LDS, 16B per lane; LDS dst = base + lane*16 (wave-uniform base)
#define GLD16(gp, lp) \
  __builtin_amdgcn_global_load_lds((__attribute__((address_space(1))) const void*)(gp), \
                                   (__attribute__((address_space(3))) void*)(lp), 16, 0, 0)

// ---------------- fused prep: fp32->bf16 cast (x,wq,wk,wv,wo) + RoPE LUT ----
// blocks 0..8191: cast (2097152 float4). blocks 8192..8447: 65536 LUT entries.
__global__ __launch_bounds__(256)
void prep_kernel(const float* __restrict__ x,  const float* __restrict__ wq,
                 const float* __restrict__ wk, const float* __restrict__ wv,
                 const float* __restrict__ wo, bf16_t* __restrict__ dst,
                 float2* __restrict__ lut) {
  if (blockIdx.x < 8192) {
    int i = blockIdx.x * 256 + threadIdx.x;   // float4 index, 0..2097151
    const float* s;
    if (i < 1048576) {
      s = x + (size_t)i * 4;
    } else {
      int j = i - 1048576;
      int w = j >> 18;                        // 262144 float4 per weight
      const float* base = (w == 0) ? wq : (w == 1) ? wk : (w == 2) ? wv : wo;
      s = base + (size_t)(j & 262143) * 4;
    }
    float4 v = *(const float4*)s;
    bf16x4_t o;
    o.x = (bf16_t)v.x; o.y = (bf16_t)v.y; o.z = (bf16_t)v.z; o.w = (bf16_t)v.w;
    ((bf16x4_t*)dst)[i] = o;
  } else {
    int i = (blockIdx.x - 8192) * 256 + threadIdx.x;  // 0..65535
    int s = i >> 5, f = i & 31;
    float ang = (float)s * exp2f(-ROPE_C * (float)f);
    float sn, cs;
    sincosf(ang, &sn, &cs);
    lut[i] = make_float2(sn, cs);
  }
}

// ---------------- fused Q/K/V GEMM: one 1024-block dispatch ----------------
// XCD-chunked swizzle (T1): swz=(id%8)*128+id/8 -> each XCD owns a contiguous
// chunk; consecutive swz share an A panel -> panel stays in that XCD's L2.
// swz 0..511:   Q/K GEMM (m97 structure, 128x128 tile, BK=32, acc[4][4])
//               bn 0..7 -> Q, bn 8..15 -> K; RoPE epilogue via lane shfl.
// swz 512..1023: V^T GEMM, 64(f)x128(t) tile, acc[2][4].
__global__ __launch_bounds__(256)
void gemm_qkv(const bf16_t* __restrict__ A, const bf16_t* __restrict__ Wq,
              const bf16_t* __restrict__ Wk, const bf16_t* __restrict__ Wv,
              const float* __restrict__ bq, const float* __restrict__ bk,
              const float* __restrict__ bv, const float2* __restrict__ lut,
              bf16_t* __restrict__ Qb, bf16_t* __restrict__ Kb,
              bf16_t* __restrict__ Vtb) {
  const int K = 1024;
  __shared__ bf16_t As[128 * 32];
  __shared__ bf16_t Bs[128 * 32];

  const int tid  = threadIdx.x;
  const int w    = tid >> 6;                // 0..3
  const int lane = tid & 63;
  const int quad = lane >> 4;
  const int lrow = lane & 15;
  const int srow = lane >> 2;               // 0..15 within 16-row chunk
  const int scol = (lane & 3) * 8;          // 0,8,16,24

  const int id  = blockIdx.x;               // 0..1023
  const int swz = (id & 7) * 128 + (id >> 3);

  if (swz < 512) {
    // ---------------- Q/K path ----------------
    const int wm = (w >> 1) * 64, wn = (w & 1) * 64;
    const int bm = swz >> 4;                // 0..31
    const int bn = swz & 15;                // 0..15

    const int isK = bn >> 3;                // 0 = Q, 1 = K (block-uniform)
    const int bnl = bn & 7;
    const bf16_t* Ablk = A + (size_t)(bm * 128) * K;
    const bf16_t* Bblk = (isK ? Wk : Wq) + (size_t)(bnl * 128) * K;
    const float*  bias = isK ? bk : bq;
    bf16_t* D = isK ? Kb : Qb;

    f32x4_t acc[4][4] = {};

    for (int k0 = 0; k0 < K; k0 += 32) {
      GLD16(&Ablk[(size_t)(w * 32 + srow) * K + k0 + scol],      &As[(w * 32) * 32]);
      GLD16(&Ablk[(size_t)(w * 32 + 16 + srow) * K + k0 + scol], &As[(w * 32 + 16) * 32]);
      GLD16(&Bblk[(size_t)(w * 32 + srow) * K + k0 + scol],      &Bs[(w * 32) * 32]);
      GLD16(&Bblk[(size_t)(w * 32 + 16 + srow) * K + k0 + scol], &Bs[(w * 32 + 16) * 32]);
      __syncthreads();

      bf16x8_t af[4], bf[4];
#pragma unroll
      for (int mi = 0; mi < 4; mi++)
        af[mi] = *(const bf16x8_t*)(&As[(wm + mi * 16 + lrow) * 32 + quad * 8]);
#pragma unroll
      for (int ni = 0; ni < 4; ni++)
        bf[ni] = *(const bf16x8_t*)(&Bs[(wn + ni * 16 + lrow) * 32 + quad * 8]);
#pragma unroll
      for (int mi = 0; mi < 4; mi++)
#pragma unroll
        for (int ni = 0; ni < 4; ni++)
          acc[mi][ni] = __builtin_amdgcn_mfma_f32_16x16x32_bf16(af[mi], bf[ni], acc[mi][ni], 0, 0, 0);
      __syncthreads();
    }

    const int brow = bm * 128 + wm;
    const int cbase = bnl * 128 + wn;

#pragma unroll
    for (int ni = 0; ni < 4; ni++) {
      const int col = cbase + ni * 16 + lrow;  // 0..1023
      const float bvv = bias[col];
      const int t = col & 63;
      const int h = col >> 6;
      const int fidx = t >> 1;
#pragma unroll
      for (int mi = 0; mi < 4; mi++) {
        f32x4_t v = acc[mi][ni];
#pragma unroll
        for (int r = 0; r < 4; r++) {
          const int row = brow + mi * 16 + quad * 4 + r;  // token
          const int s = row & (SEQ - 1);
          float val = v[r] + bvv;
          const float2 sc = lut[s * 32 + fidx];
          const float pv = __shfl_xor(val, 1);            // partner column col^1
          val = (t & 1) ? (val * sc.y + pv * sc.x) : (val * sc.y - pv * sc.x);
          const int b = row >> 11;
          const size_t o = (((size_t)(b * NH + h) * SEQ) + s) * DK + t;
          D[o] = (bf16_t)val;
        }
      }
    }
  } else {
    // ---------------- V^T path: Vt = (x Wv^T + bv)^T ----------------
    const int j = swz - 512;
    const int wm = (w >> 1) * 32, wn = (w & 1) * 64;
    const int bm = j >> 5;                  // 0..15 feature tiles
    const int bn = j & 31;                  // 0..31 token tiles

    const bf16_t* Ablk = Wv + (size_t)(bm * 64) * K;    // features
    const bf16_t* Bblk = A  + (size_t)(bn * 128) * K;   // tokens

    f32x4_t acc[2][4] = {};

    for (int k0 = 0; k0 < K; k0 += 32) {
      GLD16(&Ablk[(size_t)(w * 16 + srow) * K + k0 + scol],      &As[(w * 16) * 32]);
      GLD16(&Bblk[(size_t)(w * 32 + srow) * K + k0 + scol],      &Bs[(w * 32) * 32]);
      GLD16(&Bblk[(size_t)(w * 32 + 16 + srow) * K + k0 + scol], &Bs[(w * 32 + 16) * 32]);
      __syncthreads();

      bf16x8_t af[2], bf[4];
#pragma unroll
      for (int mi = 0; mi < 2; mi++)
        af[mi] = *(const bf16x8_t*)(&As[(wm + mi * 16 + lrow) * 32 + quad * 8]);
#pragma unroll
      for (int ni = 0; ni < 4; ni++)
        bf[ni] = *(const bf16x8_t*)(&Bs[(wn + ni * 16 + lrow) * 32 + quad * 8]);
#pragma unroll
      for (int mi = 0; mi < 2; mi++)
#pragma unroll
        for (int ni = 0; ni < 4; ni++)
          acc[mi][ni] = __builtin_amdgcn_mfma_f32_16x16x32_bf16(af[mi], bf[ni], acc[mi][ni], 0, 0, 0);
      __syncthreads();
    }

    const int fbase = bm * 64 + wm;
    const int tbase = bn * 128 + wn;

#pragma unroll
    for (int ni = 0; ni < 4; ni++) {
      const int t = tbase + ni * 16 + lrow;    // token
      const int b = t >> 11;
      const int s = t & (SEQ - 1);
#pragma unroll
      for (int mi = 0; mi < 2; mi++) {
        f32x4_t v = acc[mi][ni];
        const int f = fbase + mi * 16 + quad * 4;  // feature base (mult of 4)
        const int h = f >> 6, d = f & 63;
#pragma unroll
        for (int r = 0; r < 4; r++)
          Vtb[((size_t)((b * NH + h) * DK + d + r)) * SEQ + s] = (bf16_t)(v[r] + bv[f + r]);
      }
    }
  }
}

// ---------------- output GEMM: out = AO * Wo^T + bo, 256 thr ----------------
// 128(M)x64(N) tile, wave tile 64x32: acc[4][2] = 8 MFMA : 6 reads : 3 GLD.
// 512 blocks 1D, T1 XCD swizzle: consecutive swz share the A panel.
__global__ __launch_bounds__(256)
void gemm_out(const bf16_t* __restrict__ A, const bf16_t* __restrict__ Bw,
              const float* __restrict__ bias, float* __restrict__ D) {
  const int K = 1024;
  __shared__ bf16_t As[128 * 32];
  __shared__ bf16_t Bs[64 * 32];

  const int tid  = threadIdx.x;
  const int w    = tid >> 6;                // 0..3
  const int lane = tid & 63;
  const int quad = lane >> 4;
  const int lrow = lane & 15;
  const int wm = (w >> 1) * 64, wn = (w & 1) * 32;

  const int id  = blockIdx.x;               // 0..511
  const int swz = (id & 7) * 64 + (id >> 3);
  const int bm  = swz >> 4;                 // 0..31
  const int bn  = swz & 15;                 // 0..15

  const bf16_t* Ablk = A  + (size_t)(bm * 128) * K;
  const bf16_t* Bblk = Bw + (size_t)(bn * 64) * K;

  f32x4_t acc[4][2] = {};

  const int srow = lane >> 2;
  const int scol = (lane & 3) * 8;

  for (int k0 = 0; k0 < K; k0 += 32) {
    GLD16(&Ablk[(size_t)(w * 32 + srow) * K + k0 + scol],      &As[(w * 32) * 32]);
    GLD16(&Ablk[(size_t)(w * 32 + 16 + srow) * K + k0 + scol], &As[(w * 32 + 16) * 32]);
    GLD16(&Bblk[(size_t)(w * 16 + srow) * K + k0 + scol],      &Bs[(w * 16) * 32]);
    __syncthreads();

    bf16x8_t af[4], bf[2];
#pragma unroll
    for (int mi = 0; mi < 4; mi++)
      af[mi] = *(const bf16x8_t*)(&As[(wm + mi * 16 + lrow) * 32 + quad * 8]);
#pragma unroll
    for (int ni = 0; ni < 2; ni++)
      bf[ni] = *(const bf16x8_t*)(&Bs[(wn + ni * 16 + lrow) * 32 + quad * 8]);
#pragma unroll
    for (int mi = 0; mi < 4; mi++)
#pragma unroll
      for (int ni = 0; ni < 2; ni++)
        acc[mi][ni] = __builtin_amdgcn_mfma_f32_16x16x32_bf16(af[mi], bf[ni], acc[mi][ni], 0, 0, 0);
    __syncthreads();
  }

#pragma unroll
  for (int ni = 0; ni < 2; ni++) {
    const int col = bn * 64 + wn + ni * 16 + lrow;
    const float bvv = bias[col];
#pragma unroll
    for (int mi = 0; mi < 4; mi++) {
      f32x4_t v = acc[mi][ni];
#pragma unroll
      for (int r = 0; r < 4; r++) {
        const int row = bm * 128 + wm + mi * 16 + quad * 4 + r;
        D[(size_t)row * DM + col] = v[r] + bvv;
      }
    }
  }
}

// ---------------- flash attention v8: KVBLK=256 + T14 reg dbuf + T5 --------
// Per 256-key tile: write prefetched regs->LDS, barrier, issue next tile's
// global loads, setprio(1){compute}setprio(0), barrier. 8 tiles -> 16 barrier
// drains (was 32). LDS 70.7 KB -> still 2 blocks/CU.
// T1 swizzle: the 16 q-blocks of a head land on one XCD (K/V L2 reuse).
__global__ __launch_bounds__(512)
void attn_kernel(const bf16_t* __restrict__ Q, const bf16_t* __restrict__ K,
                 const bf16_t* __restrict__ Vt, bf16_t* __restrict__ AO) {
  __shared__ bf16_t Ks[256 * 72];        // [key][dk], stride 72 (36 dw = 4 mod 32)
  __shared__ bf16_t Vs[64 * 264];        // [dk][key], stride 264 (132 dw = 4 mod 32)

  const int tid  = threadIdx.x;
  const int w    = tid >> 6;             // 0..7
  const int lane = tid & 63;
  const int quad = lane >> 4;
  const int lrow = lane & 15;

  const int id  = blockIdx.x;            // 0..511
  const int swz = (id & 7) * 64 + (id >> 3);
  const int bh  = swz >> 4;              // 0..31
  const int q0  = (swz & 15) * 128 + w * 16;

  const bf16_t* Qh  = Q  + (size_t)bh * SEQ * DK;
  const bf16_t* Kh  = K  + (size_t)bh * SEQ * DK;
  const bf16_t* Vth = Vt + (size_t)bh * DK * SEQ;

  bf16x8_t qf[2];
#pragma unroll
  for (int c = 0; c < 2; c++) {
    bf16x8_t t = *(const bf16x8_t*)(&Qh[(size_t)(q0 + lrow) * DK + c * 32 + quad * 8]);
#pragma unroll
    for (int i = 0; i < 8; i++) t[i] = (bf16_t)((float)t[i] * EXP_C);
    qf[c] = t;
  }

  f32x4_t accO[4] = {};
  float lsum = 0.f;

  const int krA = tid >> 3;             // 0..63  (K staging: 4 rows apart by 64)
  const int kcA = (tid & 7) * 8;        // elem col (16B chunks)
  const int vrA = tid >> 5;             // 0..15  (V staging: 4 rows apart by 16)
  const int vcA = (tid & 31) * 8;       // elem col

  // prologue: prefetch tile 0 into registers (T14)
  uint4 kr[4], vr[4];
#pragma unroll
  for (int i = 0; i < 4; i++) {
    kr[i] = *(const uint4*)(&Kh[(size_t)(krA + 64 * i) * DK + kcA]);
    vr[i] = *(const uint4*)(&Vth[(size_t)(vrA + 16 * i) * SEQ + vcA]);
  }

  for (int kt = 0; kt < SEQ / 256; ++kt) {
    // commit prefetched tile to LDS
#pragma unroll
    for (int i = 0; i < 4; i++) {
      *(uint4*)(&Ks[(krA + 64 * i) * 72 + kcA])  = kr[i];
      *(uint4*)(&Vs[(vrA + 16 * i) * 264 + vcA]) = vr[i];
    }
    __syncthreads();

    // issue next tile's loads; latency hides under this tile's compute
    if (kt + 1 < SEQ / 256) {
      const int kb = (kt + 1) * 256;
#pragma unroll
      for (int i = 0; i < 4; i++) {
        kr[i] = *(const uint4*)(&Kh[(size_t)(kb + krA + 64 * i) * DK + kcA]);
        vr[i] = *(const uint4*)(&Vth[(size_t)(vrA + 16 * i) * SEQ + kb + vcA]);
      }
    }

    __builtin_amdgcn_s_setprio(1);
#pragma unroll
    for (int c2 = 0; c2 < 8; ++c2) {        // 32-key chunk
      uint2 pk[2];
#pragma unroll
      for (int kk2 = 0; kk2 < 2; ++kk2) {
        const int kk = c2 * 2 + kk2;        // 16-key tile
        bf16x8_t kf0 = *(const bf16x8_t*)(&Ks[(kk * 16 + lrow) * 72 + quad * 8]);
        bf16x8_t kf1 = *(const bf16x8_t*)(&Ks[(kk * 16 + lrow) * 72 + 32 + quad * 8]);
        f32x4_t z = {};
        z = __builtin_amdgcn_mfma_f32_16x16x32_bf16(kf0, qf[0], z, 0, 0, 0);
        z = __builtin_amdgcn_mfma_f32_16x16x32_bf16(kf1, qf[1], z, 0, 0, 0);
        const float p0 = __builtin_amdgcn_exp2f(z[0]), p1 = __builtin_amdgcn_exp2f(z[1]);
        const float p2 = __builtin_amdgcn_exp2f(z[2]), p3 = __builtin_amdgcn_exp2f(z[3]);
        lsum += (p0 + p1) + (p2 + p3);
        pk[kk2].x = __builtin_amdgcn_perm(__builtin_bit_cast(unsigned, p1),
                                          __builtin_bit_cast(unsigned, p0), 0x07060302u);
        pk[kk2].y = __builtin_amdgcn_perm(__builtin_bit_cast(unsigned, p3),
                                          __builtin_bit_cast(unsigned, p2), 0x07060302u);
      }
      uint4 pfu;
      pfu.x = pk[0].x; pfu.y = pk[0].y; pfu.z = pk[1].x; pfu.w = pk[1].y;
      bf16x8_t pf = __builtin_bit_cast(bf16x8_t, pfu);
#pragma unroll
      for (int nt = 0; nt < 4; ++nt) {
        const bf16_t* vbase = &Vs[(nt * 16 + lrow) * 264 + c2 * 32 + quad * 4];
        bf16x8_t vf;
        *(bf16x4_t*)(&vf)       = *(const bf16x4_t*)(vbase);
        *((bf16x4_t*)(&vf) + 1) = *(const bf16x4_t*)(vbase + 16);
        accO[nt] = __builtin_amdgcn_mfma_f32_16x16x32_bf16(pf, vf, accO[nt], 0, 0, 0);
      }
    }
    __builtin_amdgcn_s_setprio(0);
    __syncthreads();
  }

  lsum += __shfl_xor(lsum, 16);
  lsum += __shfl_xor(lsum, 32);
  float linv[4];
#pragma unroll
  for (int r = 0; r < 4; r++)
    linv[r] = 1.0f / __shfl(lsum, quad * 4 + r);

  const int b = bh >> 4, h = bh & 15;
#pragma unroll
  for (int nt = 0; nt < 4; nt++)
#pragma unroll
    for (int r = 0; r < 4; r++) {
      const int srowq = q0 + quad * 4 + r;
      const float val = accO[nt][r] * linv[r];
      const size_t o = ((size_t)(b * SEQ + srowq)) * DM + h * DK + nt * 16 + lrow;
      AO[o] = (bf16_t)val;
    }
}

extern "C" void kernel_launch(void* const* d_in, const int* in_sizes, int n_in,
                              void* d_out, int out_size, void* d_ws, size_t ws_size,
                              hipStream_t stream) {
  const float* x  = (const float*)d_in[0];
  const float* wq = (const float*)d_in[1];
  const float* bq = (const float*)d_in[2];
  const float* wk = (const float*)d_in[3];
  const float* bk = (const float*)d_in[4];
  const float* wv = (const float*)d_in[5];
  const float* bv = (const float*)d_in[6];
  const float* wo = (const float*)d_in[7];
  const float* bo = (const float*)d_in[8];
  float* out = (float*)d_out;

  char* ws = (char*)d_ws;
  bf16_t* xb   = (bf16_t*)(ws);             // 8 MB
  bf16_t* wqb  = (bf16_t*)(ws + 8388608);   // 2 MB
  bf16_t* wkb  = (bf16_t*)(ws + 10485760);  // 2 MB
  bf16_t* wvb  = (bf16_t*)(ws + 12582912);  // 2 MB
  bf16_t* wob  = (bf16_t*)(ws + 14680064);  // 2 MB
  bf16_t* Qb   = (bf16_t*)(ws + 16777216);  // 8 MB (B,H,S,dk)
  bf16_t* Kb   = (bf16_t*)(ws + 25165824);  // 8 MB (B,H,S,dk)
  bf16_t* Vtb  = (bf16_t*)(ws + 33554432);  // 8 MB (B,H,dk,S)
  bf16_t* AOb  = (bf16_t*)(ws + 41943040);  // 8 MB (B,S,D)
  float2* lut  = (float2*)(ws + 50331648);  // 512 KB RoPE LUT

  prep_kernel<<<8448, 256, 0, stream>>>(x, wq, wk, wv, wo, xb, lut);

  gemm_qkv<<<1024, 256, 0, stream>>>(xb, wqb, wkb, wvb, bq, bk, bv, lut, Qb, Kb, Vtb);

  attn_kernel<<<512, 512, 0, stream>>>(Qb, Kb, Vtb, AOb);

  gemm_out<<<512, 256, 0, stream>>>(AOb, wob, bo, out);
}

// Round 3
// 221.112 us; speedup vs baseline: 1.2128x; 1.2128x over previous
//
#include <hip/hip_runtime.h>
#include <hip/hip_bf16.h>
#include <math.h>

typedef __bf16 bf16_t;
typedef __bf16 bf16x4_t __attribute__((ext_vector_type(4)));
typedef __bf16 bf16x8_t __attribute__((ext_vector_type(8)));
typedef float  f32x4_t  __attribute__((ext_vector_type(4)));

#define SEQ 2048
#define DM  1024
#define NH  16
#define DK  64
// log2(10000)/32
#define ROPE_C 0.4152410118609203f
// log2(e)/sqrt(dk)
#define EXP_C (1.4426950408889634f / 8.0f)

// async global->LDS, 16B per lane; LDS dst = base + lane*16 (wave-uniform base)
#define GLD16(gp, lp) \
  __builtin_amdgcn_global_load_lds((__attribute__((address_space(1))) const void*)(gp), \
                                   (__attribute__((address_space(3))) void*)(lp), 16, 0, 0)

// ---------------- fused prep: fp32->bf16 cast (x,wq,wk,wv,wo) + RoPE LUT ----
// blocks 0..8191: cast (2097152 float4). blocks 8192..8447: 65536 LUT entries.
__global__ __launch_bounds__(256)
void prep_kernel(const float* __restrict__ x,  const float* __restrict__ wq,
                 const float* __restrict__ wk, const float* __restrict__ wv,
                 const float* __restrict__ wo, bf16_t* __restrict__ dst,
                 float2* __restrict__ lut) {
  if (blockIdx.x < 8192) {
    int i = blockIdx.x * 256 + threadIdx.x;   // float4 index, 0..2097151
    const float* s;
    if (i < 1048576) {
      s = x + (size_t)i * 4;
    } else {
      int j = i - 1048576;
      int w = j >> 18;                        // 262144 float4 per weight
      const float* base = (w == 0) ? wq : (w == 1) ? wk : (w == 2) ? wv : wo;
      s = base + (size_t)(j & 262143) * 4;
    }
    float4 v = *(const float4*)s;
    bf16x4_t o;
    o.x = (bf16_t)v.x; o.y = (bf16_t)v.y; o.z = (bf16_t)v.z; o.w = (bf16_t)v.w;
    ((bf16x4_t*)dst)[i] = o;
  } else {
    int i = (blockIdx.x - 8192) * 256 + threadIdx.x;  // 0..65535
    int s = i >> 5, f = i & 31;
    float ang = (float)s * exp2f(-ROPE_C * (float)f);
    float sn, cs;
    sincosf(ang, &sn, &cs);
    lut[i] = make_float2(sn, cs);
  }
}

// ---------------- fused Q/K/V GEMM: one 1024-block dispatch ----------------
// XCD-chunked swizzle (T1): swz=(id%8)*128+id/8 -> each XCD owns a contiguous
// chunk; consecutive swz share an A panel -> panel stays in that XCD's L2.
// swz 0..511:   Q/K GEMM (m97 structure, 128x128 tile, BK=32, acc[4][4])
//               bn 0..7 -> Q, bn 8..15 -> K; RoPE epilogue via lane shfl.
// swz 512..1023: V^T GEMM, 64(f)x128(t) tile, acc[2][4].
__global__ __launch_bounds__(256)
void gemm_qkv(const bf16_t* __restrict__ A, const bf16_t* __restrict__ Wq,
              const bf16_t* __restrict__ Wk, const bf16_t* __restrict__ Wv,
              const float* __restrict__ bq, const float* __restrict__ bk,
              const float* __restrict__ bv, const float2* __restrict__ lut,
              bf16_t* __restrict__ Qb, bf16_t* __restrict__ Kb,
              bf16_t* __restrict__ Vtb) {
  const int K = 1024;
  __shared__ bf16_t As[128 * 32];
  __shared__ bf16_t Bs[128 * 32];

  const int tid  = threadIdx.x;
  const int w    = tid >> 6;                // 0..3
  const int lane = tid & 63;
  const int quad = lane >> 4;
  const int lrow = lane & 15;
  const int srow = lane >> 2;               // 0..15 within 16-row chunk
  const int scol = (lane & 3) * 8;          // 0,8,16,24

  const int id  = blockIdx.x;               // 0..1023
  const int swz = (id & 7) * 128 + (id >> 3);

  if (swz < 512) {
    // ---------------- Q/K path ----------------
    const int wm = (w >> 1) * 64, wn = (w & 1) * 64;
    const int bm = swz >> 4;                // 0..31
    const int bn = swz & 15;                // 0..15

    const int isK = bn >> 3;                // 0 = Q, 1 = K (block-uniform)
    const int bnl = bn & 7;
    const bf16_t* Ablk = A + (size_t)(bm * 128) * K;
    const bf16_t* Bblk = (isK ? Wk : Wq) + (size_t)(bnl * 128) * K;
    const float*  bias = isK ? bk : bq;
    bf16_t* D = isK ? Kb : Qb;

    f32x4_t acc[4][4] = {};

    for (int k0 = 0; k0 < K; k0 += 32) {
      GLD16(&Ablk[(size_t)(w * 32 + srow) * K + k0 + scol],      &As[(w * 32) * 32]);
      GLD16(&Ablk[(size_t)(w * 32 + 16 + srow) * K + k0 + scol], &As[(w * 32 + 16) * 32]);
      GLD16(&Bblk[(size_t)(w * 32 + srow) * K + k0 + scol],      &Bs[(w * 32) * 32]);
      GLD16(&Bblk[(size_t)(w * 32 + 16 + srow) * K + k0 + scol], &Bs[(w * 32 + 16) * 32]);
      __syncthreads();

      bf16x8_t af[4], bf[4];
#pragma unroll
      for (int mi = 0; mi < 4; mi++)
        af[mi] = *(const bf16x8_t*)(&As[(wm + mi * 16 + lrow) * 32 + quad * 8]);
#pragma unroll
      for (int ni = 0; ni < 4; ni++)
        bf[ni] = *(const bf16x8_t*)(&Bs[(wn + ni * 16 + lrow) * 32 + quad * 8]);
#pragma unroll
      for (int mi = 0; mi < 4; mi++)
#pragma unroll
        for (int ni = 0; ni < 4; ni++)
          acc[mi][ni] = __builtin_amdgcn_mfma_f32_16x16x32_bf16(af[mi], bf[ni], acc[mi][ni], 0, 0, 0);
      __syncthreads();
    }

    const int brow = bm * 128 + wm;
    const int cbase = bnl * 128 + wn;

#pragma unroll
    for (int ni = 0; ni < 4; ni++) {
      const int col = cbase + ni * 16 + lrow;  // 0..1023
      const float bvv = bias[col];
      const int t = col & 63;
      const int h = col >> 6;
      const int fidx = t >> 1;
#pragma unroll
      for (int mi = 0; mi < 4; mi++) {
        f32x4_t v = acc[mi][ni];
#pragma unroll
        for (int r = 0; r < 4; r++) {
          const int row = brow + mi * 16 + quad * 4 + r;  // token
          const int s = row & (SEQ - 1);
          float val = v[r] + bvv;
          const float2 sc = lut[s * 32 + fidx];
          const float pv = __shfl_xor(val, 1);            // partner column col^1
          val = (t & 1) ? (val * sc.y + pv * sc.x) : (val * sc.y - pv * sc.x);
          const int b = row >> 11;
          const size_t o = (((size_t)(b * NH + h) * SEQ) + s) * DK + t;
          D[o] = (bf16_t)val;
        }
      }
    }
  } else {
    // ---------------- V^T path: Vt = (x Wv^T + bv)^T ----------------
    const int j = swz - 512;
    const int wm = (w >> 1) * 32, wn = (w & 1) * 64;
    const int bm = j >> 5;                  // 0..15 feature tiles
    const int bn = j & 31;                  // 0..31 token tiles

    const bf16_t* Ablk = Wv + (size_t)(bm * 64) * K;    // features
    const bf16_t* Bblk = A  + (size_t)(bn * 128) * K;   // tokens

    f32x4_t acc[2][4] = {};

    for (int k0 = 0; k0 < K; k0 += 32) {
      GLD16(&Ablk[(size_t)(w * 16 + srow) * K + k0 + scol],      &As[(w * 16) * 32]);
      GLD16(&Bblk[(size_t)(w * 32 + srow) * K + k0 + scol],      &Bs[(w * 32) * 32]);
      GLD16(&Bblk[(size_t)(w * 32 + 16 + srow) * K + k0 + scol], &Bs[(w * 32 + 16) * 32]);
      __syncthreads();

      bf16x8_t af[2], bf[4];
#pragma unroll
      for (int mi = 0; mi < 2; mi++)
        af[mi] = *(const bf16x8_t*)(&As[(wm + mi * 16 + lrow) * 32 + quad * 8]);
#pragma unroll
      for (int ni = 0; ni < 4; ni++)
        bf[ni] = *(const bf16x8_t*)(&Bs[(wn + ni * 16 + lrow) * 32 + quad * 8]);
#pragma unroll
      for (int mi = 0; mi < 2; mi++)
#pragma unroll
        for (int ni = 0; ni < 4; ni++)
          acc[mi][ni] = __builtin_amdgcn_mfma_f32_16x16x32_bf16(af[mi], bf[ni], acc[mi][ni], 0, 0, 0);
      __syncthreads();
    }

    const int fbase = bm * 64 + wm;
    const int tbase = bn * 128 + wn;

#pragma unroll
    for (int ni = 0; ni < 4; ni++) {
      const int t = tbase + ni * 16 + lrow;    // token
      const int b = t >> 11;
      const int s = t & (SEQ - 1);
#pragma unroll
      for (int mi = 0; mi < 2; mi++) {
        f32x4_t v = acc[mi][ni];
        const int f = fbase + mi * 16 + quad * 4;  // feature base (mult of 4)
        const int h = f >> 6, d = f & 63;
#pragma unroll
        for (int r = 0; r < 4; r++)
          Vtb[((size_t)((b * NH + h) * DK + d + r)) * SEQ + s] = (bf16_t)(v[r] + bv[f + r]);
      }
    }
  }
}

// ---------------- output GEMM: out = AO * Wo^T + bo, 256 thr ----------------
// 128(M)x64(N) tile, wave tile 64x32: acc[4][2] = 8 MFMA : 6 reads : 3 GLD.
// 512 blocks 1D, T1 XCD swizzle: consecutive swz share the A panel.
__global__ __launch_bounds__(256)
void gemm_out(const bf16_t* __restrict__ A, const bf16_t* __restrict__ Bw,
              const float* __restrict__ bias, float* __restrict__ D) {
  const int K = 1024;
  __shared__ bf16_t As[128 * 32];
  __shared__ bf16_t Bs[64 * 32];

  const int tid  = threadIdx.x;
  const int w    = tid >> 6;                // 0..3
  const int lane = tid & 63;
  const int quad = lane >> 4;
  const int lrow = lane & 15;
  const int wm = (w >> 1) * 64, wn = (w & 1) * 32;

  const int id  = blockIdx.x;               // 0..511
  const int swz = (id & 7) * 64 + (id >> 3);
  const int bm  = swz >> 4;                 // 0..31
  const int bn  = swz & 15;                 // 0..15

  const bf16_t* Ablk = A  + (size_t)(bm * 128) * K;
  const bf16_t* Bblk = Bw + (size_t)(bn * 64) * K;

  f32x4_t acc[4][2] = {};

  const int srow = lane >> 2;
  const int scol = (lane & 3) * 8;

  for (int k0 = 0; k0 < K; k0 += 32) {
    GLD16(&Ablk[(size_t)(w * 32 + srow) * K + k0 + scol],      &As[(w * 32) * 32]);
    GLD16(&Ablk[(size_t)(w * 32 + 16 + srow) * K + k0 + scol], &As[(w * 32 + 16) * 32]);
    GLD16(&Bblk[(size_t)(w * 16 + srow) * K + k0 + scol],      &Bs[(w * 16) * 32]);
    __syncthreads();

    bf16x8_t af[4], bf[2];
#pragma unroll
    for (int mi = 0; mi < 4; mi++)
      af[mi] = *(const bf16x8_t*)(&As[(wm + mi * 16 + lrow) * 32 + quad * 8]);
#pragma unroll
    for (int ni = 0; ni < 2; ni++)
      bf[ni] = *(const bf16x8_t*)(&Bs[(wn + ni * 16 + lrow) * 32 + quad * 8]);
#pragma unroll
    for (int mi = 0; mi < 4; mi++)
#pragma unroll
      for (int ni = 0; ni < 2; ni++)
        acc[mi][ni] = __builtin_amdgcn_mfma_f32_16x16x32_bf16(af[mi], bf[ni], acc[mi][ni], 0, 0, 0);
    __syncthreads();
  }

#pragma unroll
  for (int ni = 0; ni < 2; ni++) {
    const int col = bn * 64 + wn + ni * 16 + lrow;
    const float bvv = bias[col];
#pragma unroll
    for (int mi = 0; mi < 4; mi++) {
      f32x4_t v = acc[mi][ni];
#pragma unroll
      for (int r = 0; r < 4; r++) {
        const int row = bm * 128 + wm + mi * 16 + quad * 4 + r;
        D[(size_t)row * DM + col] = v[r] + bvv;
      }
    }
  }
}

// ---------------- flash attention v9: R1 body + T1 swizzle + T5 setprio ----
// KVBLK=128, T14 reg dbuf with NAMED SCALARS (R2's uint4 arrays spilled to
// scratch: WRITE_SIZE 8->251 MB). LDS 35 KB, VGPR ~40, 2+ blocks/CU.
// T1: 16 q-blocks of a head land on one XCD (K/V L2 reuse; FETCH 70->54 MB).
__global__ __launch_bounds__(512)
void attn_kernel(const bf16_t* __restrict__ Q, const bf16_t* __restrict__ K,
                 const bf16_t* __restrict__ Vt, bf16_t* __restrict__ AO) {
  __shared__ bf16_t Ks[128 * 72];        // [key][dk]
  __shared__ bf16_t Vs[64 * 136];        // [dk][key]

  const int tid  = threadIdx.x;
  const int w    = tid >> 6;             // 0..7
  const int lane = tid & 63;
  const int quad = lane >> 4;
  const int lrow = lane & 15;

  const int id  = blockIdx.x;            // 0..511
  const int swz = (id & 7) * 64 + (id >> 3);
  const int bh  = swz >> 4;              // 0..31
  const int q0  = (swz & 15) * 128 + w * 16;

  const bf16_t* Qh  = Q  + (size_t)bh * SEQ * DK;
  const bf16_t* Kh  = K  + (size_t)bh * SEQ * DK;
  const bf16_t* Vth = Vt + (size_t)bh * DK * SEQ;

  bf16x8_t qf[2];
#pragma unroll
  for (int c = 0; c < 2; c++) {
    bf16x8_t t = *(const bf16x8_t*)(&Qh[(size_t)(q0 + lrow) * DK + c * 32 + quad * 8]);
#pragma unroll
    for (int i = 0; i < 8; i++) t[i] = (bf16_t)((float)t[i] * EXP_C);
    qf[c] = t;
  }

  f32x4_t accO[4] = {};
  float lsum = 0.f;

  const int krow = tid >> 2;            // 0..127 (K staging)
  const int kcol = (tid & 3) * 16;
  const int vrow = tid >> 3;            // 0..63 (V staging)
  const int vcol = (tid & 7) * 16;

  // prologue: prefetch tile 0 into registers (named scalars - do not array!)
  uint4 kr0 = *(const uint4*)(&Kh[(size_t)krow * DK + kcol]);
  uint4 kr1 = *(const uint4*)(&Kh[(size_t)krow * DK + kcol + 8]);
  uint4 vr0 = *(const uint4*)(&Vth[(size_t)vrow * SEQ + vcol]);
  uint4 vr1 = *(const uint4*)(&Vth[(size_t)vrow * SEQ + vcol + 8]);

  for (int kt = 0; kt < SEQ / 128; ++kt) {
    // commit prefetched tile to LDS
    *(uint4*)(&Ks[krow * 72 + kcol])      = kr0;
    *(uint4*)(&Ks[krow * 72 + kcol + 8])  = kr1;
    *(uint4*)(&Vs[vrow * 136 + vcol])     = vr0;
    *(uint4*)(&Vs[vrow * 136 + vcol + 8]) = vr1;
    __syncthreads();

    // issue next tile's loads; latency hides under this tile's compute
    if (kt + 1 < SEQ / 128) {
      const int kb = (kt + 1) * 128;
      kr0 = *(const uint4*)(&Kh[(size_t)(kb + krow) * DK + kcol]);
      kr1 = *(const uint4*)(&Kh[(size_t)(kb + krow) * DK + kcol + 8]);
      vr0 = *(const uint4*)(&Vth[(size_t)vrow * SEQ + kb + vcol]);
      vr1 = *(const uint4*)(&Vth[(size_t)vrow * SEQ + kb + vcol + 8]);
    }

    __builtin_amdgcn_s_setprio(1);
#pragma unroll
    for (int c2 = 0; c2 < 4; ++c2) {        // 32-key chunk
      uint2 pk[2];
#pragma unroll
      for (int kk2 = 0; kk2 < 2; ++kk2) {
        const int kk = c2 * 2 + kk2;        // 16-key tile
        bf16x8_t kf0 = *(const bf16x8_t*)(&Ks[(kk * 16 + lrow) * 72 + quad * 8]);
        bf16x8_t kf1 = *(const bf16x8_t*)(&Ks[(kk * 16 + lrow) * 72 + 32 + quad * 8]);
        f32x4_t z = {};
        z = __builtin_amdgcn_mfma_f32_16x16x32_bf16(kf0, qf[0], z, 0, 0, 0);
        z = __builtin_amdgcn_mfma_f32_16x16x32_bf16(kf1, qf[1], z, 0, 0, 0);
        const float p0 = __builtin_amdgcn_exp2f(z[0]), p1 = __builtin_amdgcn_exp2f(z[1]);
        const float p2 = __builtin_amdgcn_exp2f(z[2]), p3 = __builtin_amdgcn_exp2f(z[3]);
        lsum += (p0 + p1) + (p2 + p3);
        pk[kk2].x = __builtin_amdgcn_perm(__builtin_bit_cast(unsigned, p1),
                                          __builtin_bit_cast(unsigned, p0), 0x07060302u);
        pk[kk2].y = __builtin_amdgcn_perm(__builtin_bit_cast(unsigned, p3),
                                          __builtin_bit_cast(unsigned, p2), 0x07060302u);
      }
      uint4 pfu;
      pfu.x = pk[0].x; pfu.y = pk[0].y; pfu.z = pk[1].x; pfu.w = pk[1].y;
      bf16x8_t pf = __builtin_bit_cast(bf16x8_t, pfu);
#pragma unroll
      for (int nt = 0; nt < 4; ++nt) {
        const bf16_t* vbase = &Vs[(nt * 16 + lrow) * 136 + c2 * 32 + quad * 4];
        bf16x8_t vf;
        *(bf16x4_t*)(&vf)       = *(const bf16x4_t*)(vbase);
        *((bf16x4_t*)(&vf) + 1) = *(const bf16x4_t*)(vbase + 16);
        accO[nt] = __builtin_amdgcn_mfma_f32_16x16x32_bf16(pf, vf, accO[nt], 0, 0, 0);
      }
    }
    __builtin_amdgcn_s_setprio(0);
    __syncthreads();
  }

  lsum += __shfl_xor(lsum, 16);
  lsum += __shfl_xor(lsum, 32);
  float linv[4];
#pragma unroll
  for (int r = 0; r < 4; r++)
    linv[r] = 1.0f / __shfl(lsum, quad * 4 + r);

  const int b = bh >> 4, h = bh & 15;
#pragma unroll
  for (int nt = 0; nt < 4; nt++)
#pragma unroll
    for (int r = 0; r < 4; r++) {
      const int srowq = q0 + quad * 4 + r;
      const float val = accO[nt][r] * linv[r];
      const size_t o = ((size_t)(b * SEQ + srowq)) * DM + h * DK + nt * 16 + lrow;
      AO[o] = (bf16_t)val;
    }
}

extern "C" void kernel_launch(void* const* d_in, const int* in_sizes, int n_in,
                              void* d_out, int out_size, void* d_ws, size_t ws_size,
                              hipStream_t stream) {
  const float* x  = (const float*)d_in[0];
  const float* wq = (const float*)d_in[1];
  const float* bq = (const float*)d_in[2];
  const float* wk = (const float*)d_in[3];
  const float* bk = (const float*)d_in[4];
  const float* wv = (const float*)d_in[5];
  const float* bv = (const float*)d_in[6];
  const float* wo = (const float*)d_in[7];
  const float* bo = (const float*)d_in[8];
  float* out = (float*)d_out;

  char* ws = (char*)d_ws;
  bf16_t* xb   = (bf16_t*)(ws);             // 8 MB
  bf16_t* wqb  = (bf16_t*)(ws + 8388608);   // 2 MB
  bf16_t* wkb  = (bf16_t*)(ws + 10485760);  // 2 MB
  bf16_t* wvb  = (bf16_t*)(ws + 12582912);  // 2 MB
  bf16_t* wob  = (bf16_t*)(ws + 14680064);  // 2 MB
  bf16_t* Qb   = (bf16_t*)(ws + 16777216);  // 8 MB (B,H,S,dk)
  bf16_t* Kb   = (bf16_t*)(ws + 25165824);  // 8 MB (B,H,S,dk)
  bf16_t* Vtb  = (bf16_t*)(ws + 33554432);  // 8 MB (B,H,dk,S)
  bf16_t* AOb  = (bf16_t*)(ws + 41943040);  // 8 MB (B,S,D)
  float2* lut  = (float2*)(ws + 50331648);  // 512 KB RoPE LUT

  prep_kernel<<<8448, 256, 0, stream>>>(x, wq, wk, wv, wo, xb, lut);

  gemm_qkv<<<1024, 256, 0, stream>>>(xb, wqb, wkb, wvb, bq, bk, bv, lut, Qb, Kb, Vtb);

  attn_kernel<<<512, 512, 0, stream>>>(Qb, Kb, Vtb, AOb);

  gemm_out<<<512, 256, 0, stream>>>(AOb, wob, bo, out);
}

// Round 4
// 204.364 us; speedup vs baseline: 1.3121x; 1.0820x over previous
//
#include <hip/hip_runtime.h>
#include <hip/hip_bf16.h>
#include <math.h>

typedef __bf16 bf16_t;
typedef __bf16 bf16x4_t __attribute__((ext_vector_type(4)));
typedef __bf16 bf16x8_t __attribute__((ext_vector_type(8)));
typedef float  f32x4_t  __attribute__((ext_vector_type(4)));

#define SEQ 2048
#define DM  1024
#define NH  16
#define DK  64
// log2(10000)/32
#define ROPE_C 0.4152410118609203f
// log2(e)/sqrt(dk)
#define EXP_C (1.4426950408889634f / 8.0f)

// async global->LDS, 16B per lane; LDS dst = base + lane*16 (wave-uniform base)
#define GLD16(gp, lp) \
  __builtin_amdgcn_global_load_lds((__attribute__((address_space(1))) const void*)(gp), \
                                   (__attribute__((address_space(3))) void*)(lp), 16, 0, 0)

// ---------------- fused prep: fp32->bf16 cast (x,wq,wk,wv,wo) + RoPE LUT ----
// blocks 0..8191: cast (2097152 float4). blocks 8192..8447: 65536 LUT entries.
__global__ __launch_bounds__(256)
void prep_kernel(const float* __restrict__ x,  const float* __restrict__ wq,
                 const float* __restrict__ wk, const float* __restrict__ wv,
                 const float* __restrict__ wo, bf16_t* __restrict__ dst,
                 float2* __restrict__ lut) {
  if (blockIdx.x < 8192) {
    int i = blockIdx.x * 256 + threadIdx.x;   // float4 index, 0..2097151
    const float* s;
    if (i < 1048576) {
      s = x + (size_t)i * 4;
    } else {
      int j = i - 1048576;
      int w = j >> 18;                        // 262144 float4 per weight
      const float* base = (w == 0) ? wq : (w == 1) ? wk : (w == 2) ? wv : wo;
      s = base + (size_t)(j & 262143) * 4;
    }
    float4 v = *(const float4*)s;
    bf16x4_t o;
    o.x = (bf16_t)v.x; o.y = (bf16_t)v.y; o.z = (bf16_t)v.z; o.w = (bf16_t)v.w;
    ((bf16x4_t*)dst)[i] = o;
  } else {
    int i = (blockIdx.x - 8192) * 256 + threadIdx.x;  // 0..65535
    int s = i >> 5, f = i & 31;
    float ang = (float)s * exp2f(-ROPE_C * (float)f);
    float sn, cs;
    sincosf(ang, &sn, &cs);
    lut[i] = make_float2(sn, cs);
  }
}

// ---------------- fused Q/K/V GEMM: one 1024-block dispatch ----------------
// XCD-chunked swizzle (T1): swz=(id%8)*128+id/8 -> each XCD owns a contiguous
// chunk; consecutive swz share an A panel -> panel stays in that XCD's L2.
// swz 0..511:   Q/K GEMM (m97 structure, 128x128 tile, BK=32, acc[4][4])
//               bn 0..7 -> Q, bn 8..15 -> K; RoPE epilogue via lane shfl.
// swz 512..1023: V^T GEMM, 64(f)x128(t) tile, acc[2][4].
__global__ __launch_bounds__(256)
void gemm_qkv(const bf16_t* __restrict__ A, const bf16_t* __restrict__ Wq,
              const bf16_t* __restrict__ Wk, const bf16_t* __restrict__ Wv,
              const float* __restrict__ bq, const float* __restrict__ bk,
              const float* __restrict__ bv, const float2* __restrict__ lut,
              bf16_t* __restrict__ Qb, bf16_t* __restrict__ Kb,
              bf16_t* __restrict__ Vtb) {
  const int K = 1024;
  __shared__ bf16_t As[128 * 32];
  __shared__ bf16_t Bs[128 * 32];

  const int tid  = threadIdx.x;
  const int w    = tid >> 6;                // 0..3
  const int lane = tid & 63;
  const int quad = lane >> 4;
  const int lrow = lane & 15;
  const int srow = lane >> 2;               // 0..15 within 16-row chunk
  const int scol = (lane & 3) * 8;          // 0,8,16,24

  const int id  = blockIdx.x;               // 0..1023
  const int swz = (id & 7) * 128 + (id >> 3);

  if (swz < 512) {
    // ---------------- Q/K path ----------------
    const int wm = (w >> 1) * 64, wn = (w & 1) * 64;
    const int bm = swz >> 4;                // 0..31
    const int bn = swz & 15;                // 0..15

    const int isK = bn >> 3;                // 0 = Q, 1 = K (block-uniform)
    const int bnl = bn & 7;
    const bf16_t* Ablk = A + (size_t)(bm * 128) * K;
    const bf16_t* Bblk = (isK ? Wk : Wq) + (size_t)(bnl * 128) * K;
    const float*  bias = isK ? bk : bq;
    bf16_t* D = isK ? Kb : Qb;

    f32x4_t acc[4][4] = {};

    for (int k0 = 0; k0 < K; k0 += 32) {
      GLD16(&Ablk[(size_t)(w * 32 + srow) * K + k0 + scol],      &As[(w * 32) * 32]);
      GLD16(&Ablk[(size_t)(w * 32 + 16 + srow) * K + k0 + scol], &As[(w * 32 + 16) * 32]);
      GLD16(&Bblk[(size_t)(w * 32 + srow) * K + k0 + scol],      &Bs[(w * 32) * 32]);
      GLD16(&Bblk[(size_t)(w * 32 + 16 + srow) * K + k0 + scol], &Bs[(w * 32 + 16) * 32]);
      __syncthreads();

      bf16x8_t af[4], bf[4];
#pragma unroll
      for (int mi = 0; mi < 4; mi++)
        af[mi] = *(const bf16x8_t*)(&As[(wm + mi * 16 + lrow) * 32 + quad * 8]);
#pragma unroll
      for (int ni = 0; ni < 4; ni++)
        bf[ni] = *(const bf16x8_t*)(&Bs[(wn + ni * 16 + lrow) * 32 + quad * 8]);
#pragma unroll
      for (int mi = 0; mi < 4; mi++)
#pragma unroll
        for (int ni = 0; ni < 4; ni++)
          acc[mi][ni] = __builtin_amdgcn_mfma_f32_16x16x32_bf16(af[mi], bf[ni], acc[mi][ni], 0, 0, 0);
      __syncthreads();
    }

    const int brow = bm * 128 + wm;
    const int cbase = bnl * 128 + wn;

#pragma unroll
    for (int ni = 0; ni < 4; ni++) {
      const int col = cbase + ni * 16 + lrow;  // 0..1023
      const float bvv = bias[col];
      const int t = col & 63;
      const int h = col >> 6;
      const int fidx = t >> 1;
#pragma unroll
      for (int mi = 0; mi < 4; mi++) {
        f32x4_t v = acc[mi][ni];
#pragma unroll
        for (int r = 0; r < 4; r++) {
          const int row = brow + mi * 16 + quad * 4 + r;  // token
          const int s = row & (SEQ - 1);
          float val = v[r] + bvv;
          const float2 sc = lut[s * 32 + fidx];
          const float pv = __shfl_xor(val, 1);            // partner column col^1
          val = (t & 1) ? (val * sc.y + pv * sc.x) : (val * sc.y - pv * sc.x);
          const int b = row >> 11;
          const size_t o = (((size_t)(b * NH + h) * SEQ) + s) * DK + t;
          D[o] = (bf16_t)val;
        }
      }
    }
  } else {
    // ---------------- V^T path: Vt = (x Wv^T + bv)^T ----------------
    const int j = swz - 512;
    const int wm = (w >> 1) * 32, wn = (w & 1) * 64;
    const int bm = j >> 5;                  // 0..15 feature tiles
    const int bn = j & 31;                  // 0..31 token tiles

    const bf16_t* Ablk = Wv + (size_t)(bm * 64) * K;    // features
    const bf16_t* Bblk = A  + (size_t)(bn * 128) * K;   // tokens

    f32x4_t acc[2][4] = {};

    for (int k0 = 0; k0 < K; k0 += 32) {
      GLD16(&Ablk[(size_t)(w * 16 + srow) * K + k0 + scol],      &As[(w * 16) * 32]);
      GLD16(&Bblk[(size_t)(w * 32 + srow) * K + k0 + scol],      &Bs[(w * 32) * 32]);
      GLD16(&Bblk[(size_t)(w * 32 + 16 + srow) * K + k0 + scol], &Bs[(w * 32 + 16) * 32]);
      __syncthreads();

      bf16x8_t af[2], bf[4];
#pragma unroll
      for (int mi = 0; mi < 2; mi++)
        af[mi] = *(const bf16x8_t*)(&As[(wm + mi * 16 + lrow) * 32 + quad * 8]);
#pragma unroll
      for (int ni = 0; ni < 4; ni++)
        bf[ni] = *(const bf16x8_t*)(&Bs[(wn + ni * 16 + lrow) * 32 + quad * 8]);
#pragma unroll
      for (int mi = 0; mi < 2; mi++)
#pragma unroll
        for (int ni = 0; ni < 4; ni++)
          acc[mi][ni] = __builtin_amdgcn_mfma_f32_16x16x32_bf16(af[mi], bf[ni], acc[mi][ni], 0, 0, 0);
      __syncthreads();
    }

    const int fbase = bm * 64 + wm;
    const int tbase = bn * 128 + wn;

#pragma unroll
    for (int ni = 0; ni < 4; ni++) {
      const int t = tbase + ni * 16 + lrow;    // token
      const int b = t >> 11;
      const int s = t & (SEQ - 1);
#pragma unroll
      for (int mi = 0; mi < 2; mi++) {
        f32x4_t v = acc[mi][ni];
        const int f = fbase + mi * 16 + quad * 4;  // feature base (mult of 4)
        const int h = f >> 6, d = f & 63;
#pragma unroll
        for (int r = 0; r < 4; r++)
          Vtb[((size_t)((b * NH + h) * DK + d + r)) * SEQ + s] = (bf16_t)(v[r] + bv[f + r]);
      }
    }
  }
}

// ---------------- output GEMM: out = AO * Wo^T + bo, 256 thr ----------------
// 128(M)x64(N) tile, wave tile 64x32: acc[4][2] = 8 MFMA : 6 reads : 3 GLD.
// 512 blocks 1D, T1 XCD swizzle: consecutive swz share the A panel.
__global__ __launch_bounds__(256)
void gemm_out(const bf16_t* __restrict__ A, const bf16_t* __restrict__ Bw,
              const float* __restrict__ bias, float* __restrict__ D) {
  const int K = 1024;
  __shared__ bf16_t As[128 * 32];
  __shared__ bf16_t Bs[64 * 32];

  const int tid  = threadIdx.x;
  const int w    = tid >> 6;                // 0..3
  const int lane = tid & 63;
  const int quad = lane >> 4;
  const int lrow = lane & 15;
  const int wm = (w >> 1) * 64, wn = (w & 1) * 32;

  const int id  = blockIdx.x;               // 0..511
  const int swz = (id & 7) * 64 + (id >> 3);
  const int bm  = swz >> 4;                 // 0..31
  const int bn  = swz & 15;                 // 0..15

  const bf16_t* Ablk = A  + (size_t)(bm * 128) * K;
  const bf16_t* Bblk = Bw + (size_t)(bn * 64) * K;

  f32x4_t acc[4][2] = {};

  const int srow = lane >> 2;
  const int scol = (lane & 3) * 8;

  for (int k0 = 0; k0 < K; k0 += 32) {
    GLD16(&Ablk[(size_t)(w * 32 + srow) * K + k0 + scol],      &As[(w * 32) * 32]);
    GLD16(&Ablk[(size_t)(w * 32 + 16 + srow) * K + k0 + scol], &As[(w * 32 + 16) * 32]);
    GLD16(&Bblk[(size_t)(w * 16 + srow) * K + k0 + scol],      &Bs[(w * 16) * 32]);
    __syncthreads();

    bf16x8_t af[4], bf[2];
#pragma unroll
    for (int mi = 0; mi < 4; mi++)
      af[mi] = *(const bf16x8_t*)(&As[(wm + mi * 16 + lrow) * 32 + quad * 8]);
#pragma unroll
    for (int ni = 0; ni < 2; ni++)
      bf[ni] = *(const bf16x8_t*)(&Bs[(wn + ni * 16 + lrow) * 32 + quad * 8]);
#pragma unroll
    for (int mi = 0; mi < 4; mi++)
#pragma unroll
      for (int ni = 0; ni < 2; ni++)
        acc[mi][ni] = __builtin_amdgcn_mfma_f32_16x16x32_bf16(af[mi], bf[ni], acc[mi][ni], 0, 0, 0);
    __syncthreads();
  }

#pragma unroll
  for (int ni = 0; ni < 2; ni++) {
    const int col = bn * 64 + wn + ni * 16 + lrow;
    const float bvv = bias[col];
#pragma unroll
    for (int mi = 0; mi < 4; mi++) {
      f32x4_t v = acc[mi][ni];
#pragma unroll
      for (int r = 0; r < 4; r++) {
        const int row = bm * 128 + wm + mi * 16 + quad * 4 + r;
        D[(size_t)row * DM + col] = v[r] + bvv;
      }
    }
  }
}

// ---------------- flash attention v10: conflict-free swizzled LDS ----------
// Diagnosis R3: LDS-bound. Old layout: K reads ~8-way conflicted (stride 36dw),
// V reads 2x b64 4-way conflicted (stride 68dw); 1.36e7 conflict-cyc/dispatch.
// New: Ks[128][64] pow-2 stride + XOR granule swizzle g^=(row&7);
//      Vs[64][128] pow-2 stride + XOR swizzle g^=(row&15) + key-permutation
//      sigma(k) = ((k&15)>>2)*8 + (k&3) + 4*(k>>4) applied at staging-write so
//      PV's 8 key-slots per lane are contiguous -> single ds_read_b128.
// All reads/writes verified uniform across 32 banks. Numerics unchanged.
__global__ __launch_bounds__(512)
void attn_kernel(const bf16_t* __restrict__ Q, const bf16_t* __restrict__ K,
                 const bf16_t* __restrict__ Vt, bf16_t* __restrict__ AO) {
  __shared__ bf16_t Ks[128 * 64];        // [key][dk] swizzled, 16 KB
  __shared__ bf16_t Vs[64 * 128];        // [dk][sigma(key)] swizzled, 16 KB

  const int tid  = threadIdx.x;
  const int w    = tid >> 6;             // 0..7
  const int lane = tid & 63;
  const int quad = lane >> 4;
  const int lrow = lane & 15;

  const int id  = blockIdx.x;            // 0..511
  const int swz = (id & 7) * 64 + (id >> 3);
  const int bh  = swz >> 4;              // 0..31
  const int q0  = (swz & 15) * 128 + w * 16;

  const bf16_t* Qh  = Q  + (size_t)bh * SEQ * DK;
  const bf16_t* Kh  = K  + (size_t)bh * SEQ * DK;
  const bf16_t* Vth = Vt + (size_t)bh * DK * SEQ;

  bf16x8_t qf[2];
#pragma unroll
  for (int c = 0; c < 2; c++) {
    bf16x8_t t = *(const bf16x8_t*)(&Qh[(size_t)(q0 + lrow) * DK + c * 32 + quad * 8]);
#pragma unroll
    for (int i = 0; i < 8; i++) t[i] = (bf16_t)((float)t[i] * EXP_C);
    qf[c] = t;
  }

  f32x4_t accO[4] = {};
  float lsum = 0.f;

  const int krow = tid >> 2;            // 0..127 (K staging row)
  const int kcol = (tid & 3) * 16;      // elem col
  const int kg0  = (tid & 3) * 2;       // logical granule (16B units)
  const int vrow = tid >> 3;            // 0..63 (V staging row)
  const int vcol = (tid & 7) * 16;      // elem col in Vt (global, unpermuted)

  // swizzled write offsets (elem units; granule = 8 elem = 16 B)
  const int kw0 = krow * 64 + ((kg0       ^ (krow & 7)) << 3);
  const int kw1 = krow * 64 + (((kg0 + 1) ^ (krow & 7)) << 3);
  const int vb  = (vcol >> 5) * 4;           // base granule of 32-key block
  const int vh  = ((vcol >> 4) & 1) * 4;     // elem offset inside granule
  const int vsw = vrow & 15;
  const int vw0 = vrow * 128 + (((vb + 0) ^ vsw) << 3) + vh;
  const int vw1 = vrow * 128 + (((vb + 1) ^ vsw) << 3) + vh;
  const int vw2 = vrow * 128 + (((vb + 2) ^ vsw) << 3) + vh;
  const int vw3 = vrow * 128 + (((vb + 3) ^ vsw) << 3) + vh;

  // prologue: prefetch tile 0 into registers (named scalars - do not array!)
  uint4 kr0 = *(const uint4*)(&Kh[(size_t)krow * DK + kcol]);
  uint4 kr1 = *(const uint4*)(&Kh[(size_t)krow * DK + kcol + 8]);
  uint4 vr0 = *(const uint4*)(&Vth[(size_t)vrow * SEQ + vcol]);
  uint4 vr1 = *(const uint4*)(&Vth[(size_t)vrow * SEQ + vcol + 8]);

  for (int kt = 0; kt < SEQ / 128; ++kt) {
    // commit prefetched tile to LDS (swizzled + sigma-permuted)
    *(uint4*)(&Ks[kw0]) = kr0;
    *(uint4*)(&Ks[kw1]) = kr1;
    *(uint2*)(&Vs[vw0]) = make_uint2(vr0.x, vr0.y);
    *(uint2*)(&Vs[vw1]) = make_uint2(vr0.z, vr0.w);
    *(uint2*)(&Vs[vw2]) = make_uint2(vr1.x, vr1.y);
    *(uint2*)(&Vs[vw3]) = make_uint2(vr1.z, vr1.w);
    __syncthreads();

    // issue next tile's loads; latency hides under this tile's compute
    if (kt + 1 < SEQ / 128) {
      const int kb = (kt + 1) * 128;
      kr0 = *(const uint4*)(&Kh[(size_t)(kb + krow) * DK + kcol]);
      kr1 = *(const uint4*)(&Kh[(size_t)(kb + krow) * DK + kcol + 8]);
      vr0 = *(const uint4*)(&Vth[(size_t)vrow * SEQ + kb + vcol]);
      vr1 = *(const uint4*)(&Vth[(size_t)vrow * SEQ + kb + vcol + 8]);
    }

    __builtin_amdgcn_s_setprio(1);
#pragma unroll
    for (int c2 = 0; c2 < 4; ++c2) {        // 32-key chunk
      uint2 pk[2];
#pragma unroll
      for (int kk2 = 0; kk2 < 2; ++kk2) {
        const int kk = c2 * 2 + kk2;        // 16-key tile
        const int krd = (kk * 16 + lrow) * 64;
        bf16x8_t kf0 = *(const bf16x8_t*)(&Ks[krd + ((quad       ^ (lrow & 7)) << 3)]);
        bf16x8_t kf1 = *(const bf16x8_t*)(&Ks[krd + (((quad + 4) ^ (lrow & 7)) << 3)]);
        f32x4_t z = {};
        z = __builtin_amdgcn_mfma_f32_16x16x32_bf16(kf0, qf[0], z, 0, 0, 0);
        z = __builtin_amdgcn_mfma_f32_16x16x32_bf16(kf1, qf[1], z, 0, 0, 0);
        const float p0 = __builtin_amdgcn_exp2f(z[0]), p1 = __builtin_amdgcn_exp2f(z[1]);
        const float p2 = __builtin_amdgcn_exp2f(z[2]), p3 = __builtin_amdgcn_exp2f(z[3]);
        lsum += (p0 + p1) + (p2 + p3);
        pk[kk2].x = __builtin_amdgcn_perm(__builtin_bit_cast(unsigned, p1),
                                          __builtin_bit_cast(unsigned, p0), 0x07060302u);
        pk[kk2].y = __builtin_amdgcn_perm(__builtin_bit_cast(unsigned, p3),
                                          __builtin_bit_cast(unsigned, p2), 0x07060302u);
      }
      uint4 pfu;
      pfu.x = pk[0].x; pfu.y = pk[0].y; pfu.z = pk[1].x; pfu.w = pk[1].y;
      bf16x8_t pf = __builtin_bit_cast(bf16x8_t, pfu);
#pragma unroll
      for (int nt = 0; nt < 4; ++nt) {
        // sigma-permuted V: lane's 8 key-slots contiguous at granule c2*4+quad
        bf16x8_t vf = *(const bf16x8_t*)(
            &Vs[(nt * 16 + lrow) * 128 + ((((c2 << 2) | quad) ^ lrow) << 3)]);
        accO[nt] = __builtin_amdgcn_mfma_f32_16x16x32_bf16(pf, vf, accO[nt], 0, 0, 0);
      }
    }
    __builtin_amdgcn_s_setprio(0);
    __syncthreads();
  }

  lsum += __shfl_xor(lsum, 16);
  lsum += __shfl_xor(lsum, 32);
  float linv[4];
#pragma unroll
  for (int r = 0; r < 4; r++)
    linv[r] = 1.0f / __shfl(lsum, quad * 4 + r);

  const int b = bh >> 4, h = bh & 15;
#pragma unroll
  for (int nt = 0; nt < 4; nt++)
#pragma unroll
    for (int r = 0; r < 4; r++) {
      const int srowq = q0 + quad * 4 + r;
      const float val = accO[nt][r] * linv[r];
      const size_t o = ((size_t)(b * SEQ + srowq)) * DM + h * DK + nt * 16 + lrow;
      AO[o] = (bf16_t)val;
    }
}

extern "C" void kernel_launch(void* const* d_in, const int* in_sizes, int n_in,
                              void* d_out, int out_size, void* d_ws, size_t ws_size,
                              hipStream_t stream) {
  const float* x  = (const float*)d_in[0];
  const float* wq = (const float*)d_in[1];
  const float* bq = (const float*)d_in[2];
  const float* wk = (const float*)d_in[3];
  const float* bk = (const float*)d_in[4];
  const float* wv = (const float*)d_in[5];
  const float* bv = (const float*)d_in[6];
  const float* wo = (const float*)d_in[7];
  const float* bo = (const float*)d_in[8];
  float* out = (float*)d_out;

  char* ws = (char*)d_ws;
  bf16_t* xb   = (bf16_t*)(ws);             // 8 MB
  bf16_t* wqb  = (bf16_t*)(ws + 8388608);   // 2 MB
  bf16_t* wkb  = (bf16_t*)(ws + 10485760);  // 2 MB
  bf16_t* wvb  = (bf16_t*)(ws + 12582912);  // 2 MB
  bf16_t* wob  = (bf16_t*)(ws + 14680064);  // 2 MB
  bf16_t* Qb   = (bf16_t*)(ws + 16777216);  // 8 MB (B,H,S,dk)
  bf16_t* Kb   = (bf16_t*)(ws + 25165824);  // 8 MB (B,H,S,dk)
  bf16_t* Vtb  = (bf16_t*)(ws + 33554432);  // 8 MB (B,H,dk,S)
  bf16_t* AOb  = (bf16_t*)(ws + 41943040);  // 8 MB (B,S,D)
  float2* lut  = (float2*)(ws + 50331648);  // 512 KB RoPE LUT

  prep_kernel<<<8448, 256, 0, stream>>>(x, wq, wk, wv, wo, xb, lut);

  gemm_qkv<<<1024, 256, 0, stream>>>(xb, wqb, wkb, wvb, bq, bk, bv, lut, Qb, Kb, Vtb);

  attn_kernel<<<512, 512, 0, stream>>>(Qb, Kb, Vtb, AOb);

  gemm_out<<<512, 256, 0, stream>>>(AOb, wob, bo, out);
}

// Round 5
// 195.854 us; speedup vs baseline: 1.3692x; 1.0435x over previous
//
#include <hip/hip_runtime.h>
#include <hip/hip_bf16.h>
#include <math.h>

typedef __bf16 bf16_t;
typedef __bf16 bf16x4_t __attribute__((ext_vector_type(4)));
typedef __bf16 bf16x8_t __attribute__((ext_vector_type(8)));
typedef float  f32x4_t  __attribute__((ext_vector_type(4)));

#define SEQ 2048
#define DM  1024
#define NH  16
#define DK  64
// log2(10000)/32
#define ROPE_C 0.4152410118609203f
// log2(e)/sqrt(dk)
#define EXP_C (1.4426950408889634f / 8.0f)

// async global->LDS, 16B per lane; LDS dst = base + lane*16 (wave-uniform base)
#define GLD16(gp, lp) \
  __builtin_amdgcn_global_load_lds((__attribute__((address_space(1))) const void*)(gp), \
                                   (__attribute__((address_space(3))) void*)(lp), 16, 0, 0)

// ---------------- fused prep: fp32->bf16 cast (x,wq,wk,wv,wo) + RoPE LUT ----
// blocks 0..8191: cast (2097152 float4). blocks 8192..8447: 65536 LUT entries.
__global__ __launch_bounds__(256)
void prep_kernel(const float* __restrict__ x,  const float* __restrict__ wq,
                 const float* __restrict__ wk, const float* __restrict__ wv,
                 const float* __restrict__ wo, bf16_t* __restrict__ dst,
                 float2* __restrict__ lut) {
  if (blockIdx.x < 8192) {
    int i = blockIdx.x * 256 + threadIdx.x;   // float4 index, 0..2097151
    const float* s;
    if (i < 1048576) {
      s = x + (size_t)i * 4;
    } else {
      int j = i - 1048576;
      int w = j >> 18;                        // 262144 float4 per weight
      const float* base = (w == 0) ? wq : (w == 1) ? wk : (w == 2) ? wv : wo;
      s = base + (size_t)(j & 262143) * 4;
    }
    float4 v = *(const float4*)s;
    bf16x4_t o;
    o.x = (bf16_t)v.x; o.y = (bf16_t)v.y; o.z = (bf16_t)v.z; o.w = (bf16_t)v.w;
    ((bf16x4_t*)dst)[i] = o;
  } else {
    int i = (blockIdx.x - 8192) * 256 + threadIdx.x;  // 0..65535
    int s = i >> 5, f = i & 31;
    float ang = (float)s * exp2f(-ROPE_C * (float)f);
    float sn, cs;
    sincosf(ang, &sn, &cs);
    lut[i] = make_float2(sn, cs);
  }
}

// ---------------- fused Q/K/V GEMM: 768 uniform-cost blocks ----------------
// R4 bug: swz-range split put all QK blocks on XCDs 0-3, all (half-cost) V
// blocks on XCDs 4-7 -> half the machine idled ~45% of the dispatch.
// Fix: V^T path now uses the SAME 128x128 tile / acc[4][4] / 16-MFMA loop as
// QK (uniform per-block cost), and work is dealt per-XCD explicitly:
//   xcd = id&7, rank = id>>3 (0..95); rank<64 -> QK, else V.
//   QK: bm in [xcd*4,xcd*4+4) x 16 bn  (A-panel stays in XCD L2)
//   V : token panel in [xcd*4,xcd*4+4) x 8 feature tiles (Wv 2MB/XCD)
// 768 blocks = exactly 3/CU; uniform cost => balanced under any dispatch.
__global__ __launch_bounds__(256)
void gemm_qkv(const bf16_t* __restrict__ A, const bf16_t* __restrict__ Wq,
              const bf16_t* __restrict__ Wk, const bf16_t* __restrict__ Wv,
              const float* __restrict__ bq, const float* __restrict__ bk,
              const float* __restrict__ bv, const float2* __restrict__ lut,
              bf16_t* __restrict__ Qb, bf16_t* __restrict__ Kb,
              bf16_t* __restrict__ Vtb) {
  const int K = 1024;
  __shared__ bf16_t As[128 * 32];
  __shared__ bf16_t Bs[128 * 32];

  const int tid  = threadIdx.x;
  const int w    = tid >> 6;                // 0..3
  const int lane = tid & 63;
  const int quad = lane >> 4;
  const int lrow = lane & 15;
  const int srow = lane >> 2;               // 0..15 within 16-row chunk
  const int scol = (lane & 3) * 8;          // 0,8,16,24
  const int wm = (w >> 1) * 64, wn = (w & 1) * 64;

  const int id   = blockIdx.x;              // 0..767
  const int xcd  = id & 7;
  const int rank = id >> 3;                 // 0..95
  const int isV  = rank >= 64;              // block-uniform

  const bf16_t* Ablk;
  const bf16_t* Bblk;
  int bmQK = 0, bnl = 0, isK = 0, bmF = 0, bnT = 0;
  if (!isV) {
    const int q = xcd * 64 + rank;          // 0..511
    bmQK = q >> 4;                          // token tile, [xcd*4, xcd*4+4)
    const int bn = q & 15;
    isK = bn >> 3;                          // 0 = Q, 1 = K
    bnl = bn & 7;
    Ablk = A + (size_t)(bmQK * 128) * K;
    Bblk = (isK ? Wk : Wq) + (size_t)(bnl * 128) * K;
  } else {
    const int v = xcd * 32 + (rank - 64);   // 0..255
    bnT = v >> 3;                           // token tile, [xcd*4, xcd*4+4)
    bmF = v & 7;                            // feature tile 0..7
    Ablk = Wv + (size_t)(bmF * 128) * K;    // 128 feature rows
    Bblk = A + (size_t)(bnT * 128) * K;     // 128 token rows
  }

  f32x4_t acc[4][4] = {};

  for (int k0 = 0; k0 < K; k0 += 32) {
    GLD16(&Ablk[(size_t)(w * 32 + srow) * K + k0 + scol],      &As[(w * 32) * 32]);
    GLD16(&Ablk[(size_t)(w * 32 + 16 + srow) * K + k0 + scol], &As[(w * 32 + 16) * 32]);
    GLD16(&Bblk[(size_t)(w * 32 + srow) * K + k0 + scol],      &Bs[(w * 32) * 32]);
    GLD16(&Bblk[(size_t)(w * 32 + 16 + srow) * K + k0 + scol], &Bs[(w * 32 + 16) * 32]);
    __syncthreads();

    bf16x8_t af[4], bf[4];
#pragma unroll
    for (int mi = 0; mi < 4; mi++)
      af[mi] = *(const bf16x8_t*)(&As[(wm + mi * 16 + lrow) * 32 + quad * 8]);
#pragma unroll
    for (int ni = 0; ni < 4; ni++)
      bf[ni] = *(const bf16x8_t*)(&Bs[(wn + ni * 16 + lrow) * 32 + quad * 8]);
#pragma unroll
    for (int mi = 0; mi < 4; mi++)
#pragma unroll
      for (int ni = 0; ni < 4; ni++)
        acc[mi][ni] = __builtin_amdgcn_mfma_f32_16x16x32_bf16(af[mi], bf[ni], acc[mi][ni], 0, 0, 0);
    __syncthreads();
  }

  if (!isV) {
    // ---------------- Q/K epilogue: bias + RoPE + scatter ----------------
    const int brow = bmQK * 128 + wm;
    const int cbase = bnl * 128 + wn;
    const float* bias = isK ? bk : bq;
    bf16_t* D = isK ? Kb : Qb;

#pragma unroll
    for (int ni = 0; ni < 4; ni++) {
      const int col = cbase + ni * 16 + lrow;  // 0..1023
      const float bvv = bias[col];
      const int t = col & 63;
      const int h = col >> 6;
      const int fidx = t >> 1;
#pragma unroll
      for (int mi = 0; mi < 4; mi++) {
        f32x4_t v = acc[mi][ni];
#pragma unroll
        for (int r = 0; r < 4; r++) {
          const int row = brow + mi * 16 + quad * 4 + r;  // token
          const int s = row & (SEQ - 1);
          float val = v[r] + bvv;
          const float2 sc = lut[s * 32 + fidx];
          const float pv = __shfl_xor(val, 1);            // partner column col^1
          val = (t & 1) ? (val * sc.y + pv * sc.x) : (val * sc.y - pv * sc.x);
          const int b = row >> 11;
          const size_t o = (((size_t)(b * NH + h) * SEQ) + s) * DK + t;
          D[o] = (bf16_t)val;
        }
      }
    }
  } else {
    // ---------------- V^T epilogue: Vt[(b,h,d), s] = C[f, t] + bv --------
    const int fbase = bmF * 128 + wm;
    const int tbase = bnT * 128 + wn;

#pragma unroll
    for (int ni = 0; ni < 4; ni++) {
      const int t = tbase + ni * 16 + lrow;    // token
      const int b = t >> 11;
      const int s = t & (SEQ - 1);
#pragma unroll
      for (int mi = 0; mi < 4; mi++) {
        f32x4_t v = acc[mi][ni];
        const int f = fbase + mi * 16 + quad * 4;  // feature base (mult of 4)
        const int h = f >> 6, d = f & 63;          // d+3 <= 63, never crosses head
#pragma unroll
        for (int r = 0; r < 4; r++)
          Vtb[((size_t)((b * NH + h) * DK + d + r)) * SEQ + s] = (bf16_t)(v[r] + bv[f + r]);
      }
    }
  }
}

// ---------------- output GEMM: out = AO * Wo^T + bo, 256 thr ----------------
// 128(M)x64(N) tile, wave tile 64x32: acc[4][2] = 8 MFMA : 6 reads : 3 GLD.
// 512 blocks 1D, T1 XCD swizzle: consecutive swz share the A panel.
__global__ __launch_bounds__(256)
void gemm_out(const bf16_t* __restrict__ A, const bf16_t* __restrict__ Bw,
              const float* __restrict__ bias, float* __restrict__ D) {
  const int K = 1024;
  __shared__ bf16_t As[128 * 32];
  __shared__ bf16_t Bs[64 * 32];

  const int tid  = threadIdx.x;
  const int w    = tid >> 6;                // 0..3
  const int lane = tid & 63;
  const int quad = lane >> 4;
  const int lrow = lane & 15;
  const int wm = (w >> 1) * 64, wn = (w & 1) * 32;

  const int id  = blockIdx.x;               // 0..511
  const int swz = (id & 7) * 64 + (id >> 3);
  const int bm  = swz >> 4;                 // 0..31
  const int bn  = swz & 15;                 // 0..15

  const bf16_t* Ablk = A  + (size_t)(bm * 128) * K;
  const bf16_t* Bblk = Bw + (size_t)(bn * 64) * K;

  f32x4_t acc[4][2] = {};

  const int srow = lane >> 2;
  const int scol = (lane & 3) * 8;

  for (int k0 = 0; k0 < K; k0 += 32) {
    GLD16(&Ablk[(size_t)(w * 32 + srow) * K + k0 + scol],      &As[(w * 32) * 32]);
    GLD16(&Ablk[(size_t)(w * 32 + 16 + srow) * K + k0 + scol], &As[(w * 32 + 16) * 32]);
    GLD16(&Bblk[(size_t)(w * 16 + srow) * K + k0 + scol],      &Bs[(w * 16) * 32]);
    __syncthreads();

    bf16x8_t af[4], bf[2];
#pragma unroll
    for (int mi = 0; mi < 4; mi++)
      af[mi] = *(const bf16x8_t*)(&As[(wm + mi * 16 + lrow) * 32 + quad * 8]);
#pragma unroll
    for (int ni = 0; ni < 2; ni++)
      bf[ni] = *(const bf16x8_t*)(&Bs[(wn + ni * 16 + lrow) * 32 + quad * 8]);
#pragma unroll
    for (int mi = 0; mi < 4; mi++)
#pragma unroll
      for (int ni = 0; ni < 2; ni++)
        acc[mi][ni] = __builtin_amdgcn_mfma_f32_16x16x32_bf16(af[mi], bf[ni], acc[mi][ni], 0, 0, 0);
    __syncthreads();
  }

#pragma unroll
  for (int ni = 0; ni < 2; ni++) {
    const int col = bn * 64 + wn + ni * 16 + lrow;
    const float bvv = bias[col];
#pragma unroll
    for (int mi = 0; mi < 4; mi++) {
      f32x4_t v = acc[mi][ni];
#pragma unroll
      for (int r = 0; r < 4; r++) {
        const int row = bm * 128 + wm + mi * 16 + quad * 4 + r;
        D[(size_t)row * DM + col] = v[r] + bvv;
      }
    }
  }
}

// ---------------- flash attention v10: conflict-free swizzled LDS ----------
// Diagnosis R3: LDS-bound. Old layout: K reads ~8-way conflicted (stride 36dw),
// V reads 2x b64 4-way conflicted (stride 68dw); 1.36e7 conflict-cyc/dispatch.
// New: Ks[128][64] pow-2 stride + XOR granule swizzle g^=(row&7);
//      Vs[64][128] pow-2 stride + XOR swizzle g^=(row&15) + key-permutation
//      sigma(k) = ((k&15)>>2)*8 + (k&3) + 4*(k>>4) applied at staging-write so
//      PV's 8 key-slots per lane are contiguous -> single ds_read_b128.
// All reads/writes verified uniform across 32 banks. Numerics unchanged.
__global__ __launch_bounds__(512)
void attn_kernel(const bf16_t* __restrict__ Q, const bf16_t* __restrict__ K,
                 const bf16_t* __restrict__ Vt, bf16_t* __restrict__ AO) {
  __shared__ bf16_t Ks[128 * 64];        // [key][dk] swizzled, 16 KB
  __shared__ bf16_t Vs[64 * 128];        // [dk][sigma(key)] swizzled, 16 KB

  const int tid  = threadIdx.x;
  const int w    = tid >> 6;             // 0..7
  const int lane = tid & 63;
  const int quad = lane >> 4;
  const int lrow = lane & 15;

  const int id  = blockIdx.x;            // 0..511
  const int swz = (id & 7) * 64 + (id >> 3);
  const int bh  = swz >> 4;              // 0..31
  const int q0  = (swz & 15) * 128 + w * 16;

  const bf16_t* Qh  = Q  + (size_t)bh * SEQ * DK;
  const bf16_t* Kh  = K  + (size_t)bh * SEQ * DK;
  const bf16_t* Vth = Vt + (size_t)bh * DK * SEQ;

  bf16x8_t qf[2];
#pragma unroll
  for (int c = 0; c < 2; c++) {
    bf16x8_t t = *(const bf16x8_t*)(&Qh[(size_t)(q0 + lrow) * DK + c * 32 + quad * 8]);
#pragma unroll
    for (int i = 0; i < 8; i++) t[i] = (bf16_t)((float)t[i] * EXP_C);
    qf[c] = t;
  }

  f32x4_t accO[4] = {};
  float lsum = 0.f;

  const int krow = tid >> 2;            // 0..127 (K staging row)
  const int kcol = (tid & 3) * 16;      // elem col
  const int kg0  = (tid & 3) * 2;       // logical granule (16B units)
  const int vrow = tid >> 3;            // 0..63 (V staging row)
  const int vcol = (tid & 7) * 16;      // elem col in Vt (global, unpermuted)

  // swizzled write offsets (elem units; granule = 8 elem = 16 B)
  const int kw0 = krow * 64 + ((kg0       ^ (krow & 7)) << 3);
  const int kw1 = krow * 64 + (((kg0 + 1) ^ (krow & 7)) << 3);
  const int vb  = (vcol >> 5) * 4;           // base granule of 32-key block
  const int vh  = ((vcol >> 4) & 1) * 4;     // elem offset inside granule
  const int vsw = vrow & 15;
  const int vw0 = vrow * 128 + (((vb + 0) ^ vsw) << 3) + vh;
  const int vw1 = vrow * 128 + (((vb + 1) ^ vsw) << 3) + vh;
  const int vw2 = vrow * 128 + (((vb + 2) ^ vsw) << 3) + vh;
  const int vw3 = vrow * 128 + (((vb + 3) ^ vsw) << 3) + vh;

  // prologue: prefetch tile 0 into registers (named scalars - do not array!)
  uint4 kr0 = *(const uint4*)(&Kh[(size_t)krow * DK + kcol]);
  uint4 kr1 = *(const uint4*)(&Kh[(size_t)krow * DK + kcol + 8]);
  uint4 vr0 = *(const uint4*)(&Vth[(size_t)vrow * SEQ + vcol]);
  uint4 vr1 = *(const uint4*)(&Vth[(size_t)vrow * SEQ + vcol + 8]);

  for (int kt = 0; kt < SEQ / 128; ++kt) {
    // commit prefetched tile to LDS (swizzled + sigma-permuted)
    *(uint4*)(&Ks[kw0]) = kr0;
    *(uint4*)(&Ks[kw1]) = kr1;
    *(uint2*)(&Vs[vw0]) = make_uint2(vr0.x, vr0.y);
    *(uint2*)(&Vs[vw1]) = make_uint2(vr0.z, vr0.w);
    *(uint2*)(&Vs[vw2]) = make_uint2(vr1.x, vr1.y);
    *(uint2*)(&Vs[vw3]) = make_uint2(vr1.z, vr1.w);
    __syncthreads();

    // issue next tile's loads; latency hides under this tile's compute
    if (kt + 1 < SEQ / 128) {
      const int kb = (kt + 1) * 128;
      kr0 = *(const uint4*)(&Kh[(size_t)(kb + krow) * DK + kcol]);
      kr1 = *(const uint4*)(&Kh[(size_t)(kb + krow) * DK + kcol + 8]);
      vr0 = *(const uint4*)(&Vth[(size_t)vrow * SEQ + kb + vcol]);
      vr1 = *(const uint4*)(&Vth[(size_t)vrow * SEQ + kb + vcol + 8]);
    }

    __builtin_amdgcn_s_setprio(1);
#pragma unroll
    for (int c2 = 0; c2 < 4; ++c2) {        // 32-key chunk
      uint2 pk[2];
#pragma unroll
      for (int kk2 = 0; kk2 < 2; ++kk2) {
        const int kk = c2 * 2 + kk2;        // 16-key tile
        const int krd = (kk * 16 + lrow) * 64;
        bf16x8_t kf0 = *(const bf16x8_t*)(&Ks[krd + ((quad       ^ (lrow & 7)) << 3)]);
        bf16x8_t kf1 = *(const bf16x8_t*)(&Ks[krd + (((quad + 4) ^ (lrow & 7)) << 3)]);
        f32x4_t z = {};
        z = __builtin_amdgcn_mfma_f32_16x16x32_bf16(kf0, qf[0], z, 0, 0, 0);
        z = __builtin_amdgcn_mfma_f32_16x16x32_bf16(kf1, qf[1], z, 0, 0, 0);
        const float p0 = __builtin_amdgcn_exp2f(z[0]), p1 = __builtin_amdgcn_exp2f(z[1]);
        const float p2 = __builtin_amdgcn_exp2f(z[2]), p3 = __builtin_amdgcn_exp2f(z[3]);
        lsum += (p0 + p1) + (p2 + p3);
        pk[kk2].x = __builtin_amdgcn_perm(__builtin_bit_cast(unsigned, p1),
                                          __builtin_bit_cast(unsigned, p0), 0x07060302u);
        pk[kk2].y = __builtin_amdgcn_perm(__builtin_bit_cast(unsigned, p3),
                                          __builtin_bit_cast(unsigned, p2), 0x07060302u);
      }
      uint4 pfu;
      pfu.x = pk[0].x; pfu.y = pk[0].y; pfu.z = pk[1].x; pfu.w = pk[1].y;
      bf16x8_t pf = __builtin_bit_cast(bf16x8_t, pfu);
#pragma unroll
      for (int nt = 0; nt < 4; ++nt) {
        // sigma-permuted V: lane's 8 key-slots contiguous at granule c2*4+quad
        bf16x8_t vf = *(const bf16x8_t*)(
            &Vs[(nt * 16 + lrow) * 128 + ((((c2 << 2) | quad) ^ lrow) << 3)]);
        accO[nt] = __builtin_amdgcn_mfma_f32_16x16x32_bf16(pf, vf, accO[nt], 0, 0, 0);
      }
    }
    __builtin_amdgcn_s_setprio(0);
    __syncthreads();
  }

  lsum += __shfl_xor(lsum, 16);
  lsum += __shfl_xor(lsum, 32);
  float linv[4];
#pragma unroll
  for (int r = 0; r < 4; r++)
    linv[r] = 1.0f / __shfl(lsum, quad * 4 + r);

  const int b = bh >> 4, h = bh & 15;
#pragma unroll
  for (int nt = 0; nt < 4; nt++)
#pragma unroll
    for (int r = 0; r < 4; r++) {
      const int srowq = q0 + quad * 4 + r;
      const float val = accO[nt][r] * linv[r];
      const size_t o = ((size_t)(b * SEQ + srowq)) * DM + h * DK + nt * 16 + lrow;
      AO[o] = (bf16_t)val;
    }
}

extern "C" void kernel_launch(void* const* d_in, const int* in_sizes, int n_in,
                              void* d_out, int out_size, void* d_ws, size_t ws_size,
                              hipStream_t stream) {
  const float* x  = (const float*)d_in[0];
  const float* wq = (const float*)d_in[1];
  const float* bq = (const float*)d_in[2];
  const float* wk = (const float*)d_in[3];
  const float* bk = (const float*)d_in[4];
  const float* wv = (const float*)d_in[5];
  const float* bv = (const float*)d_in[6];
  const float* wo = (const float*)d_in[7];
  const float* bo = (const float*)d_in[8];
  float* out = (float*)d_out;

  char* ws = (char*)d_ws;
  bf16_t* xb   = (bf16_t*)(ws);             // 8 MB
  bf16_t* wqb  = (bf16_t*)(ws + 8388608);   // 2 MB
  bf16_t* wkb  = (bf16_t*)(ws + 10485760);  // 2 MB
  bf16_t* wvb  = (bf16_t*)(ws + 12582912);  // 2 MB
  bf16_t* wob  = (bf16_t*)(ws + 14680064);  // 2 MB
  bf16_t* Qb   = (bf16_t*)(ws + 16777216);  // 8 MB (B,H,S,dk)
  bf16_t* Kb   = (bf16_t*)(ws + 25165824);  // 8 MB (B,H,S,dk)
  bf16_t* Vtb  = (bf16_t*)(ws + 33554432);  // 8 MB (B,H,dk,S)
  bf16_t* AOb  = (bf16_t*)(ws + 41943040);  // 8 MB (B,S,D)
  float2* lut  = (float2*)(ws + 50331648);  // 512 KB RoPE LUT

  prep_kernel<<<8448, 256, 0, stream>>>(x, wq, wk, wv, wo, xb, lut);

  gemm_qkv<<<768, 256, 0, stream>>>(xb, wqb, wkb, wvb, bq, bk, bv, lut, Qb, Kb, Vtb);

  attn_kernel<<<512, 512, 0, stream>>>(Qb, Kb, Vtb, AOb);

  gemm_out<<<512, 256, 0, stream>>>(AOb, wob, bo, out);
}

// Round 6
// 179.020 us; speedup vs baseline: 1.4979x; 1.0940x over previous
//
#include <hip/hip_runtime.h>
#include <hip/hip_bf16.h>
#include <math.h>

typedef __bf16 bf16_t;
typedef __bf16 bf16x4_t __attribute__((ext_vector_type(4)));
typedef __bf16 bf16x8_t __attribute__((ext_vector_type(8)));
typedef float  f32x4_t  __attribute__((ext_vector_type(4)));

#define SEQ 2048
#define DM  1024
#define NH  16
#define DK  64
// log2(10000)/32
#define ROPE_C 0.4152410118609203f
// log2(e)/sqrt(dk)
#define EXP_C (1.4426950408889634f / 8.0f)

// async global->LDS, 16B per lane; LDS dst = base + lane*16 (wave-uniform base)
#define GLD16(gp, lp) \
  __builtin_amdgcn_global_load_lds((__attribute__((address_space(1))) const void*)(gp), \
                                   (__attribute__((address_space(3))) void*)(lp), 16, 0, 0)

// ---------------- fused prep: fp32->bf16 cast (x,wq,wk,wv,wo) + RoPE LUT ----
// blocks 0..8191: cast (2097152 float4). blocks 8192..8447: 65536 LUT entries.
__global__ __launch_bounds__(256)
void prep_kernel(const float* __restrict__ x,  const float* __restrict__ wq,
                 const float* __restrict__ wk, const float* __restrict__ wv,
                 const float* __restrict__ wo, bf16_t* __restrict__ dst,
                 float2* __restrict__ lut) {
  if (blockIdx.x < 8192) {
    int i = blockIdx.x * 256 + threadIdx.x;   // float4 index, 0..2097151
    const float* s;
    if (i < 1048576) {
      s = x + (size_t)i * 4;
    } else {
      int j = i - 1048576;
      int w = j >> 18;                        // 262144 float4 per weight
      const float* base = (w == 0) ? wq : (w == 1) ? wk : (w == 2) ? wv : wo;
      s = base + (size_t)(j & 262143) * 4;
    }
    float4 v = *(const float4*)s;
    bf16x4_t o;
    o.x = (bf16_t)v.x; o.y = (bf16_t)v.y; o.z = (bf16_t)v.z; o.w = (bf16_t)v.w;
    ((bf16x4_t*)dst)[i] = o;
  } else {
    int i = (blockIdx.x - 8192) * 256 + threadIdx.x;  // 0..65535
    int s = i >> 5, f = i & 31;
    float ang = (float)s * exp2f(-ROPE_C * (float)f);
    float sn, cs;
    sincosf(ang, &sn, &cs);
    lut[i] = make_float2(sn, cs);
  }
}

// ---------------- fused Q/K/V GEMM: BK=64, swizzled LDS, 768 blocks --------
// R5 diagnosis: latency-bound on the per-step vmcnt(0)+barrier drain (32 steps).
// BK=64 halves the steps to 16 (2x compute per drain). Linear [128][64] would
// be a 16-way bank conflict (m201), and GLD16 writes linearly -> T2 swizzle in
// the both-sides form (rule 21c): linear LDS dst, PRE-SWIZZLED global source
// col ((lane&7)^(lane>>3))*8, XOR-swizzled read granule (kk*4+quad)^(lrow&7).
// Same proven pattern as attn's Ks. LDS 32 KB. Work dealing unchanged (R5):
// xcd=id&7, rank=id>>3; rank<64 -> QK, else V (uniform 128x128/acc[4][4]).
__global__ __launch_bounds__(256, 3)
void gemm_qkv(const bf16_t* __restrict__ A, const bf16_t* __restrict__ Wq,
              const bf16_t* __restrict__ Wk, const bf16_t* __restrict__ Wv,
              const float* __restrict__ bq, const float* __restrict__ bk,
              const float* __restrict__ bv, const float2* __restrict__ lut,
              bf16_t* __restrict__ Qb, bf16_t* __restrict__ Kb,
              bf16_t* __restrict__ Vtb) {
  const int K = 1024;
  __shared__ bf16_t As[128 * 64];           // 16 KB, granule-swizzled
  __shared__ bf16_t Bs[128 * 64];           // 16 KB

  const int tid  = threadIdx.x;
  const int w    = tid >> 6;                // 0..3
  const int lane = tid & 63;
  const int quad = lane >> 4;
  const int lrow = lane & 15;
  const int wm = (w >> 1) * 64, wn = (w & 1) * 64;

  // staging: per GLD16, wave covers 8 rows x 8 granules (16B each).
  // source col pre-swizzled so linear LDS slot (r,g) holds granule g^(r&7).
  const int srow8 = lane >> 3;                        // 0..7
  const int scolz = (((lane & 7) ^ (lane >> 3)) * 8); // pre-swizzled col

  const int id   = blockIdx.x;              // 0..767
  const int xcd  = id & 7;
  const int rank = id >> 3;                 // 0..95
  const int isV  = rank >= 64;              // block-uniform

  const bf16_t* Ablk;
  const bf16_t* Bblk;
  int bmQK = 0, bnl = 0, isK = 0, bmF = 0, bnT = 0;
  if (!isV) {
    const int q = xcd * 64 + rank;          // 0..511
    bmQK = q >> 4;                          // token tile, [xcd*4, xcd*4+4)
    const int bn = q & 15;
    isK = bn >> 3;                          // 0 = Q, 1 = K
    bnl = bn & 7;
    Ablk = A + (size_t)(bmQK * 128) * K;
    Bblk = (isK ? Wk : Wq) + (size_t)(bnl * 128) * K;
  } else {
    const int v = xcd * 32 + (rank - 64);   // 0..255
    bnT = v >> 3;                           // token tile, [xcd*4, xcd*4+4)
    bmF = v & 7;                            // feature tile 0..7
    Ablk = Wv + (size_t)(bmF * 128) * K;    // 128 feature rows
    Bblk = A + (size_t)(bnT * 128) * K;     // 128 token rows
  }

  f32x4_t acc[4][4] = {};

  for (int k0 = 0; k0 < K; k0 += 64) {
#pragma unroll
    for (int i = 0; i < 4; i++) {
      GLD16(&Ablk[(size_t)(w * 32 + i * 8 + srow8) * K + k0 + scolz], &As[(w * 32 + i * 8) * 64]);
      GLD16(&Bblk[(size_t)(w * 32 + i * 8 + srow8) * K + k0 + scolz], &Bs[(w * 32 + i * 8) * 64]);
    }
    __syncthreads();

#pragma unroll
    for (int kk = 0; kk < 2; kk++) {
      const int gsw = (((kk << 2) | quad) ^ (lrow & 7)) * 8;  // swizzled granule
      bf16x8_t af[4], bf[4];
#pragma unroll
      for (int mi = 0; mi < 4; mi++)
        af[mi] = *(const bf16x8_t*)(&As[(wm + mi * 16 + lrow) * 64 + gsw]);
#pragma unroll
      for (int ni = 0; ni < 4; ni++)
        bf[ni] = *(const bf16x8_t*)(&Bs[(wn + ni * 16 + lrow) * 64 + gsw]);
#pragma unroll
      for (int mi = 0; mi < 4; mi++)
#pragma unroll
        for (int ni = 0; ni < 4; ni++)
          acc[mi][ni] = __builtin_amdgcn_mfma_f32_16x16x32_bf16(af[mi], bf[ni], acc[mi][ni], 0, 0, 0);
    }
    __syncthreads();
  }

  if (!isV) {
    // ---------------- Q/K epilogue: bias + RoPE + scatter ----------------
    const int brow = bmQK * 128 + wm;
    const int cbase = bnl * 128 + wn;
    const float* bias = isK ? bk : bq;
    bf16_t* D = isK ? Kb : Qb;

#pragma unroll
    for (int ni = 0; ni < 4; ni++) {
      const int col = cbase + ni * 16 + lrow;  // 0..1023
      const float bvv = bias[col];
      const int t = col & 63;
      const int h = col >> 6;
      const int fidx = t >> 1;
#pragma unroll
      for (int mi = 0; mi < 4; mi++) {
        f32x4_t v = acc[mi][ni];
#pragma unroll
        for (int r = 0; r < 4; r++) {
          const int row = brow + mi * 16 + quad * 4 + r;  // token
          const int s = row & (SEQ - 1);
          float val = v[r] + bvv;
          const float2 sc = lut[s * 32 + fidx];
          const float pv = __shfl_xor(val, 1);            // partner column col^1
          val = (t & 1) ? (val * sc.y + pv * sc.x) : (val * sc.y - pv * sc.x);
          const int b = row >> 11;
          const size_t o = (((size_t)(b * NH + h) * SEQ) + s) * DK + t;
          D[o] = (bf16_t)val;
        }
      }
    }
  } else {
    // ---------------- V^T epilogue: Vt[(b,h,d), s] = C[f, t] + bv --------
    const int fbase = bmF * 128 + wm;
    const int tbase = bnT * 128 + wn;

#pragma unroll
    for (int ni = 0; ni < 4; ni++) {
      const int t = tbase + ni * 16 + lrow;    // token
      const int b = t >> 11;
      const int s = t & (SEQ - 1);
#pragma unroll
      for (int mi = 0; mi < 4; mi++) {
        f32x4_t v = acc[mi][ni];
        const int f = fbase + mi * 16 + quad * 4;  // feature base (mult of 4)
        const int h = f >> 6, d = f & 63;          // d+3 <= 63, never crosses head
#pragma unroll
        for (int r = 0; r < 4; r++)
          Vtb[((size_t)((b * NH + h) * DK + d + r)) * SEQ + s] = (bf16_t)(v[r] + bv[f + r]);
      }
    }
  }
}

// ---------------- output GEMM: out = AO * Wo^T + bo, 256 thr ----------------
// 128(M)x64(N) tile, wave tile 64x32: acc[4][2] = 8 MFMA : 6 reads : 3 GLD.
// 512 blocks 1D, T1 XCD swizzle: consecutive swz share the A panel.
__global__ __launch_bounds__(256)
void gemm_out(const bf16_t* __restrict__ A, const bf16_t* __restrict__ Bw,
              const float* __restrict__ bias, float* __restrict__ D) {
  const int K = 1024;
  __shared__ bf16_t As[128 * 32];
  __shared__ bf16_t Bs[64 * 32];

  const int tid  = threadIdx.x;
  const int w    = tid >> 6;                // 0..3
  const int lane = tid & 63;
  const int quad = lane >> 4;
  const int lrow = lane & 15;
  const int wm = (w >> 1) * 64, wn = (w & 1) * 32;

  const int id  = blockIdx.x;               // 0..511
  const int swz = (id & 7) * 64 + (id >> 3);
  const int bm  = swz >> 4;                 // 0..31
  const int bn  = swz & 15;                 // 0..15

  const bf16_t* Ablk = A  + (size_t)(bm * 128) * K;
  const bf16_t* Bblk = Bw + (size_t)(bn * 64) * K;

  f32x4_t acc[4][2] = {};

  const int srow = lane >> 2;
  const int scol = (lane & 3) * 8;

  for (int k0 = 0; k0 < K; k0 += 32) {
    GLD16(&Ablk[(size_t)(w * 32 + srow) * K + k0 + scol],      &As[(w * 32) * 32]);
    GLD16(&Ablk[(size_t)(w * 32 + 16 + srow) * K + k0 + scol], &As[(w * 32 + 16) * 32]);
    GLD16(&Bblk[(size_t)(w * 16 + srow) * K + k0 + scol],      &Bs[(w * 16) * 32]);
    __syncthreads();

    bf16x8_t af[4], bf[2];
#pragma unroll
    for (int mi = 0; mi < 4; mi++)
      af[mi] = *(const bf16x8_t*)(&As[(wm + mi * 16 + lrow) * 32 + quad * 8]);
#pragma unroll
    for (int ni = 0; ni < 2; ni++)
      bf[ni] = *(const bf16x8_t*)(&Bs[(wn + ni * 16 + lrow) * 32 + quad * 8]);
#pragma unroll
    for (int mi = 0; mi < 4; mi++)
#pragma unroll
      for (int ni = 0; ni < 2; ni++)
        acc[mi][ni] = __builtin_amdgcn_mfma_f32_16x16x32_bf16(af[mi], bf[ni], acc[mi][ni], 0, 0, 0);
    __syncthreads();
  }

#pragma unroll
  for (int ni = 0; ni < 2; ni++) {
    const int col = bn * 64 + wn + ni * 16 + lrow;
    const float bvv = bias[col];
#pragma unroll
    for (int mi = 0; mi < 4; mi++) {
      f32x4_t v = acc[mi][ni];
#pragma unroll
      for (int r = 0; r < 4; r++) {
        const int row = bm * 128 + wm + mi * 16 + quad * 4 + r;
        D[(size_t)row * DM + col] = v[r] + bvv;
      }
    }
  }
}

// ---------------- flash attention v10: conflict-free swizzled LDS ----------
// Diagnosis R3: LDS-bound. Old layout: K reads ~8-way conflicted (stride 36dw),
// V reads 2x b64 4-way conflicted (stride 68dw); 1.36e7 conflict-cyc/dispatch.
// New: Ks[128][64] pow-2 stride + XOR granule swizzle g^=(row&7);
//      Vs[64][128] pow-2 stride + XOR swizzle g^=(row&15) + key-permutation
//      sigma(k) = ((k&15)>>2)*8 + (k&3) + 4*(k>>4) applied at staging-write so
//      PV's 8 key-slots per lane are contiguous -> single ds_read_b128.
// All reads/writes verified uniform across 32 banks. Numerics unchanged.
__global__ __launch_bounds__(512)
void attn_kernel(const bf16_t* __restrict__ Q, const bf16_t* __restrict__ K,
                 const bf16_t* __restrict__ Vt, bf16_t* __restrict__ AO) {
  __shared__ bf16_t Ks[128 * 64];        // [key][dk] swizzled, 16 KB
  __shared__ bf16_t Vs[64 * 128];        // [dk][sigma(key)] swizzled, 16 KB

  const int tid  = threadIdx.x;
  const int w    = tid >> 6;             // 0..7
  const int lane = tid & 63;
  const int quad = lane >> 4;
  const int lrow = lane & 15;

  const int id  = blockIdx.x;            // 0..511
  const int swz = (id & 7) * 64 + (id >> 3);
  const int bh  = swz >> 4;              // 0..31
  const int q0  = (swz & 15) * 128 + w * 16;

  const bf16_t* Qh  = Q  + (size_t)bh * SEQ * DK;
  const bf16_t* Kh  = K  + (size_t)bh * SEQ * DK;
  const bf16_t* Vth = Vt + (size_t)bh * DK * SEQ;

  bf16x8_t qf[2];
#pragma unroll
  for (int c = 0; c < 2; c++) {
    bf16x8_t t = *(const bf16x8_t*)(&Qh[(size_t)(q0 + lrow) * DK + c * 32 + quad * 8]);
#pragma unroll
    for (int i = 0; i < 8; i++) t[i] = (bf16_t)((float)t[i] * EXP_C);
    qf[c] = t;
  }

  f32x4_t accO[4] = {};
  float lsum = 0.f;

  const int krow = tid >> 2;            // 0..127 (K staging row)
  const int kcol = (tid & 3) * 16;      // elem col
  const int kg0  = (tid & 3) * 2;       // logical granule (16B units)
  const int vrow = tid >> 3;            // 0..63 (V staging row)
  const int vcol = (tid & 7) * 16;      // elem col in Vt (global, unpermuted)

  // swizzled write offsets (elem units; granule = 8 elem = 16 B)
  const int kw0 = krow * 64 + ((kg0       ^ (krow & 7)) << 3);
  const int kw1 = krow * 64 + (((kg0 + 1) ^ (krow & 7)) << 3);
  const int vb  = (vcol >> 5) * 4;           // base granule of 32-key block
  const int vh  = ((vcol >> 4) & 1) * 4;     // elem offset inside granule
  const int vsw = vrow & 15;
  const int vw0 = vrow * 128 + (((vb + 0) ^ vsw) << 3) + vh;
  const int vw1 = vrow * 128 + (((vb + 1) ^ vsw) << 3) + vh;
  const int vw2 = vrow * 128 + (((vb + 2) ^ vsw) << 3) + vh;
  const int vw3 = vrow * 128 + (((vb + 3) ^ vsw) << 3) + vh;

  // prologue: prefetch tile 0 into registers (named scalars - do not array!)
  uint4 kr0 = *(const uint4*)(&Kh[(size_t)krow * DK + kcol]);
  uint4 kr1 = *(const uint4*)(&Kh[(size_t)krow * DK + kcol + 8]);
  uint4 vr0 = *(const uint4*)(&Vth[(size_t)vrow * SEQ + vcol]);
  uint4 vr1 = *(const uint4*)(&Vth[(size_t)vrow * SEQ + vcol + 8]);

  for (int kt = 0; kt < SEQ / 128; ++kt) {
    // commit prefetched tile to LDS (swizzled + sigma-permuted)
    *(uint4*)(&Ks[kw0]) = kr0;
    *(uint4*)(&Ks[kw1]) = kr1;
    *(uint2*)(&Vs[vw0]) = make_uint2(vr0.x, vr0.y);
    *(uint2*)(&Vs[vw1]) = make_uint2(vr0.z, vr0.w);
    *(uint2*)(&Vs[vw2]) = make_uint2(vr1.x, vr1.y);
    *(uint2*)(&Vs[vw3]) = make_uint2(vr1.z, vr1.w);
    __syncthreads();

    // issue next tile's loads; latency hides under this tile's compute
    if (kt + 1 < SEQ / 128) {
      const int kb = (kt + 1) * 128;
      kr0 = *(const uint4*)(&Kh[(size_t)(kb + krow) * DK + kcol]);
      kr1 = *(const uint4*)(&Kh[(size_t)(kb + krow) * DK + kcol + 8]);
      vr0 = *(const uint4*)(&Vth[(size_t)vrow * SEQ + kb + vcol]);
      vr1 = *(const uint4*)(&Vth[(size_t)vrow * SEQ + kb + vcol + 8]);
    }

    __builtin_amdgcn_s_setprio(1);
#pragma unroll
    for (int c2 = 0; c2 < 4; ++c2) {        // 32-key chunk
      uint2 pk[2];
#pragma unroll
      for (int kk2 = 0; kk2 < 2; ++kk2) {
        const int kk = c2 * 2 + kk2;        // 16-key tile
        const int krd = (kk * 16 + lrow) * 64;
        bf16x8_t kf0 = *(const bf16x8_t*)(&Ks[krd + ((quad       ^ (lrow & 7)) << 3)]);
        bf16x8_t kf1 = *(const bf16x8_t*)(&Ks[krd + (((quad + 4) ^ (lrow & 7)) << 3)]);
        f32x4_t z = {};
        z = __builtin_amdgcn_mfma_f32_16x16x32_bf16(kf0, qf[0], z, 0, 0, 0);
        z = __builtin_amdgcn_mfma_f32_16x16x32_bf16(kf1, qf[1], z, 0, 0, 0);
        const float p0 = __builtin_amdgcn_exp2f(z[0]), p1 = __builtin_amdgcn_exp2f(z[1]);
        const float p2 = __builtin_amdgcn_exp2f(z[2]), p3 = __builtin_amdgcn_exp2f(z[3]);
        lsum += (p0 + p1) + (p2 + p3);
        pk[kk2].x = __builtin_amdgcn_perm(__builtin_bit_cast(unsigned, p1),
                                          __builtin_bit_cast(unsigned, p0), 0x07060302u);
        pk[kk2].y = __builtin_amdgcn_perm(__builtin_bit_cast(unsigned, p3),
                                          __builtin_bit_cast(unsigned, p2), 0x07060302u);
      }
      uint4 pfu;
      pfu.x = pk[0].x; pfu.y = pk[0].y; pfu.z = pk[1].x; pfu.w = pk[1].y;
      bf16x8_t pf = __builtin_bit_cast(bf16x8_t, pfu);
#pragma unroll
      for (int nt = 0; nt < 4; ++nt) {
        // sigma-permuted V: lane's 8 key-slots contiguous at granule c2*4+quad
        bf16x8_t vf = *(const bf16x8_t*)(
            &Vs[(nt * 16 + lrow) * 128 + ((((c2 << 2) | quad) ^ lrow) << 3)]);
        accO[nt] = __builtin_amdgcn_mfma_f32_16x16x32_bf16(pf, vf, accO[nt], 0, 0, 0);
      }
    }
    __builtin_amdgcn_s_setprio(0);
    __syncthreads();
  }

  lsum += __shfl_xor(lsum, 16);
  lsum += __shfl_xor(lsum, 32);
  float linv[4];
#pragma unroll
  for (int r = 0; r < 4; r++)
    linv[r] = 1.0f / __shfl(lsum, quad * 4 + r);

  const int b = bh >> 4, h = bh & 15;
#pragma unroll
  for (int nt = 0; nt < 4; nt++)
#pragma unroll
    for (int r = 0; r < 4; r++) {
      const int srowq = q0 + quad * 4 + r;
      const float val = accO[nt][r] * linv[r];
      const size_t o = ((size_t)(b * SEQ + srowq)) * DM + h * DK + nt * 16 + lrow;
      AO[o] = (bf16_t)val;
    }
}

extern "C" void kernel_launch(void* const* d_in, const int* in_sizes, int n_in,
                              void* d_out, int out_size, void* d_ws, size_t ws_size,
                              hipStream_t stream) {
  const float* x  = (const float*)d_in[0];
  const float* wq = (const float*)d_in[1];
  const float* bq = (const float*)d_in[2];
  const float* wk = (const float*)d_in[3];
  const float* bk = (const float*)d_in[4];
  const float* wv = (const float*)d_in[5];
  const float* bv = (const float*)d_in[6];
  const float* wo = (const float*)d_in[7];
  const float* bo = (const float*)d_in[8];
  float* out = (float*)d_out;

  char* ws = (char*)d_ws;
  bf16_t* xb   = (bf16_t*)(ws);             // 8 MB
  bf16_t* wqb  = (bf16_t*)(ws + 8388608);   // 2 MB
  bf16_t* wkb  = (bf16_t*)(ws + 10485760);  // 2 MB
  bf16_t* wvb  = (bf16_t*)(ws + 12582912);  // 2 MB
  bf16_t* wob  = (bf16_t*)(ws + 14680064);  // 2 MB
  bf16_t* Qb   = (bf16_t*)(ws + 16777216);  // 8 MB (B,H,S,dk)
  bf16_t* Kb   = (bf16_t*)(ws + 25165824);  // 8 MB (B,H,S,dk)
  bf16_t* Vtb  = (bf16_t*)(ws + 33554432);  // 8 MB (B,H,dk,S)
  bf16_t* AOb  = (bf16_t*)(ws + 41943040);  // 8 MB (B,S,D)
  float2* lut  = (float2*)(ws + 50331648);  // 512 KB RoPE LUT

  prep_kernel<<<8448, 256, 0, stream>>>(x, wq, wk, wv, wo, xb, lut);

  gemm_qkv<<<768, 256, 0, stream>>>(xb, wqb, wkb, wvb, bq, bk, bv, lut, Qb, Kb, Vtb);

  attn_kernel<<<512, 512, 0, stream>>>(Qb, Kb, Vtb, AOb);

  gemm_out<<<512, 256, 0, stream>>>(AOb, wob, bo, out);
}